// Round 1
// baseline (567.524 us; speedup 1.0000x reference)
//
#include <hip/hip_runtime.h>
#include <hip/hip_bf16.h>
#include <math.h>

#define D_MODEL 1024
#define N_HEAD  16
#define HD      64
#define B_SZ    4
#define T_SEQ   2048
#define M_TOT   (B_SZ * T_SEQ)   // 8192
#define N_TOT   (3 * D_MODEL)    // 3072

typedef __bf16 bf16_t;
typedef __bf16 bf16x8 __attribute__((ext_vector_type(8)));
typedef __bf16 bf16x4 __attribute__((ext_vector_type(4)));
typedef float  f32x4  __attribute__((ext_vector_type(4)));

// ---------------- fp32 -> bf16 conversion (vectorized) ----------------
__global__ __launch_bounds__(256) void cvt_f32_bf16(const float* __restrict__ in,
                                                    bf16_t* __restrict__ out, int n4) {
  int i = blockIdx.x * blockDim.x + threadIdx.x;
  int stride = gridDim.x * blockDim.x;
  for (; i < n4; i += stride) {
    float4 v = ((const float4*)in)[i];
    bf16x4 o;
    o[0] = (bf16_t)v.x; o[1] = (bf16_t)v.y; o[2] = (bf16_t)v.z; o[3] = (bf16_t)v.w;
    ((bf16x4*)out)[i] = o;
  }
}

// ---------------- QKV projection GEMM (bf16 MFMA, 128x128 tile) ----------------
// C[m][n] = sum_k x[m][k] * W[n][k];  writes Q(scaled), K as [B,H,T,64], V^T as [B,H,64,T]
__global__ __launch_bounds__(256) void qkv_gemm(const bf16_t* __restrict__ xb,
                                                const bf16_t* __restrict__ wb,
                                                bf16_t* __restrict__ Q,
                                                bf16_t* __restrict__ K,
                                                bf16_t* __restrict__ Vt) {
  __shared__ alignas(16) bf16_t a_lds[128 * 32];
  __shared__ alignas(16) bf16_t b_lds[128 * 32];
  const int tid  = threadIdx.x;
  const int wave = tid >> 6;
  const int lane = tid & 63;
  const int bm = blockIdx.y * 128;
  const int bn = blockIdx.x * 128;

  f32x4 acc[4][4] = {};

  const int aRow = lane >> 2;        // 0..15 within 16-row chunk
  const int aK8  = (lane & 3) * 8;   // 0,8,16,24
  const int fr   = lane & 15;
  const int fk   = (lane >> 4) * 8;
  const int wm   = (wave >> 1) * 64;
  const int wn   = (wave & 1) * 64;

  for (int kk = 0; kk < D_MODEL; kk += 32) {
#pragma unroll
    for (int c = 0; c < 2; ++c) {
      const int chunk = wave * 2 + c;            // 0..7, 16 rows each
      const bf16_t* gA = &xb[(size_t)(bm + chunk * 16 + aRow) * D_MODEL + kk + aK8];
      __builtin_amdgcn_global_load_lds(
          (__attribute__((address_space(1))) void*)(void*)gA,
          (__attribute__((address_space(3))) void*)&a_lds[chunk * 512], 16, 0, 0);
      const bf16_t* gB = &wb[(size_t)(bn + chunk * 16 + aRow) * D_MODEL + kk + aK8];
      __builtin_amdgcn_global_load_lds(
          (__attribute__((address_space(1))) void*)(void*)gB,
          (__attribute__((address_space(3))) void*)&b_lds[chunk * 512], 16, 0, 0);
    }
    __syncthreads();

    bf16x8 af[4], bfr[4];
#pragma unroll
    for (int mt = 0; mt < 4; ++mt)
      af[mt] = *(const bf16x8*)&a_lds[(wm + mt * 16 + fr) * 32 + fk];
#pragma unroll
    for (int nt = 0; nt < 4; ++nt)
      bfr[nt] = *(const bf16x8*)&b_lds[(wn + nt * 16 + fr) * 32 + fk];
#pragma unroll
    for (int mt = 0; mt < 4; ++mt)
#pragma unroll
      for (int nt = 0; nt < 4; ++nt)
        acc[mt][nt] = __builtin_amdgcn_mfma_f32_16x16x32_bf16(af[mt], bfr[nt], acc[mt][nt], 0, 0, 0);
    __syncthreads();
  }

  // epilogue: scatter into Q (scaled), K, V^T
  const int cRowBase = (lane >> 4) * 4;
  const int cCol     = lane & 15;
#pragma unroll
  for (int mt = 0; mt < 4; ++mt) {
#pragma unroll
    for (int nt = 0; nt < 4; ++nt) {
      const int n   = bn + wn + nt * 16 + cCol;
      const int sec = n >> 10;            // 0=Q 1=K 2=V
      const int hn  = n & 1023;
      const int h   = hn >> 6;
      const int d   = hn & 63;
#pragma unroll
      for (int r = 0; r < 4; ++r) {
        const int m = bm + wm + mt * 16 + cRowBase + r;
        const int b = m >> 11;
        const int t = m & 2047;
        const float v = acc[mt][nt][r];
        if (sec == 0) {
          Q[((size_t)(b * N_HEAD + h) * T_SEQ + t) * HD + d] = (bf16_t)(v * 0.125f);
        } else if (sec == 1) {
          K[((size_t)(b * N_HEAD + h) * T_SEQ + t) * HD + d] = (bf16_t)v;
        } else {
          Vt[((size_t)(b * N_HEAD + h) * HD + d) * T_SEQ + t] = (bf16_t)v;
        }
      }
    }
  }
}

// ---------------- causal flash attention (bf16 MFMA) ----------------
// Q [BH, T, 64] (pre-scaled), K [BH, T, 64], Vt [BH, 64, T], out fp32 [BH, T, 64]
__global__ __launch_bounds__(256) void attn_fwd(const bf16_t* __restrict__ Q,
                                                const bf16_t* __restrict__ K,
                                                const bf16_t* __restrict__ Vt,
                                                float* __restrict__ out) {
  __shared__ alignas(16) bf16_t p_lds[4][16][32];
  const int tid  = threadIdx.x;
  const int wave = tid >> 6;
  const int lane = tid & 63;
  const int bh    = blockIdx.y;       // 0..63
  const int qbase = blockIdx.x * 64;  // q-block of 64 rows
  const int q0    = qbase + wave * 16;

  const bf16_t* Qp = Q  + (size_t)bh * T_SEQ * HD;
  const bf16_t* Kp = K  + (size_t)bh * T_SEQ * HD;
  const bf16_t* Vp = Vt + (size_t)bh * HD * T_SEQ;

  const int fr = lane & 15;
  const int fk = (lane >> 4) * 8;

  bf16x8 qf0 = *(const bf16x8*)&Qp[(size_t)(q0 + fr) * HD + fk];
  bf16x8 qf1 = *(const bf16x8*)&Qp[(size_t)(q0 + fr) * HD + 32 + fk];

  float m_i[4], l_i[4];
  f32x4 o_acc[4] = {};
#pragma unroll
  for (int r = 0; r < 4; ++r) { m_i[r] = -INFINITY; l_i[r] = 0.f; }

  const int kv_end = qbase + 64;   // uniform across all 4 waves (syncthreads-legal)
  const int rowBase = q0 + (lane >> 4) * 4;

  for (int kv0 = 0; kv0 < kv_end; kv0 += 32) {
    // S = Q K^T  (two 16-col tiles)
    f32x4 s[2] = {};
#pragma unroll
    for (int ct = 0; ct < 2; ++ct) {
      bf16x8 kf0 = *(const bf16x8*)&Kp[(size_t)(kv0 + ct * 16 + fr) * HD + fk];
      bf16x8 kf1 = *(const bf16x8*)&Kp[(size_t)(kv0 + ct * 16 + fr) * HD + 32 + fk];
      s[ct] = __builtin_amdgcn_mfma_f32_16x16x32_bf16(qf0, kf0, s[ct], 0, 0, 0);
      s[ct] = __builtin_amdgcn_mfma_f32_16x16x32_bf16(qf1, kf1, s[ct], 0, 0, 0);
    }
    // causal mask + row max (rows live across 16-lane groups)
    float mt_r[4];
#pragma unroll
    for (int r = 0; r < 4; ++r) {
      const int qrow = rowBase + r;
#pragma unroll
      for (int ct = 0; ct < 2; ++ct) {
        const int key = kv0 + ct * 16 + fr;
        if (key > qrow) s[ct][r] = -INFINITY;
      }
      float mx = fmaxf(s[0][r], s[1][r]);
      mx = fmaxf(mx, __shfl_xor(mx, 1));
      mx = fmaxf(mx, __shfl_xor(mx, 2));
      mx = fmaxf(mx, __shfl_xor(mx, 4));
      mx = fmaxf(mx, __shfl_xor(mx, 8));
      mt_r[r] = mx;
    }
    // online softmax update + stage P to LDS (A-fragment relayout)
#pragma unroll
    for (int r = 0; r < 4; ++r) {
      const float m_new = fmaxf(m_i[r], mt_r[r]);
      const float alpha = __expf(m_i[r] - m_new);   // -inf -> 0 on first tile
      const float p0 = __expf(s[0][r] - m_new);
      const float p1 = __expf(s[1][r] - m_new);
      float ps = p0 + p1;
      ps += __shfl_xor(ps, 1);
      ps += __shfl_xor(ps, 2);
      ps += __shfl_xor(ps, 4);
      ps += __shfl_xor(ps, 8);
      l_i[r] = l_i[r] * alpha + ps;
      m_i[r] = m_new;
#pragma unroll
      for (int ctd = 0; ctd < 4; ++ctd) o_acc[ctd][r] *= alpha;
      p_lds[wave][(lane >> 4) * 4 + r][fr]      = (bf16_t)p0;
      p_lds[wave][(lane >> 4) * 4 + r][16 + fr] = (bf16_t)p1;
    }
    __syncthreads();
    // O += P @ V   (P: 16x32 from LDS; V^T rows contiguous in key)
    bf16x8 pa = *(const bf16x8*)&p_lds[wave][fr][fk];
#pragma unroll
    for (int ctd = 0; ctd < 4; ++ctd) {
      bf16x8 vf = *(const bf16x8*)&Vp[(size_t)(ctd * 16 + fr) * T_SEQ + kv0 + fk];
      o_acc[ctd] = __builtin_amdgcn_mfma_f32_16x16x32_bf16(pa, vf, o_acc[ctd], 0, 0, 0);
    }
    __syncthreads();
  }

  // epilogue: out = O / l
  float* op = out + (size_t)bh * T_SEQ * HD;
#pragma unroll
  for (int ctd = 0; ctd < 4; ++ctd) {
#pragma unroll
    for (int r = 0; r < 4; ++r) {
      const int qrow = q0 + (lane >> 4) * 4 + r;
      op[(size_t)qrow * HD + ctd * 16 + fr] = o_acc[ctd][r] / l_i[r];
    }
  }
}

extern "C" void kernel_launch(void* const* d_in, const int* in_sizes, int n_in,
                              void* d_out, int out_size, void* d_ws, size_t ws_size,
                              hipStream_t stream) {
  const float* x = (const float*)d_in[0];
  const float* W = (const float*)d_in[1];
  float* out = (float*)d_out;

  char* ws = (char*)d_ws;
  bf16_t* xb  = (bf16_t*)(ws);                              // 16 MB
  bf16_t* wb  = (bf16_t*)(ws + 16777216);                   // 6 MB
  bf16_t* Qb  = (bf16_t*)(ws + 16777216 + 6291456);         // 16 MB
  bf16_t* Kb  = Qb + 8388608;                               // 16 MB
  bf16_t* Vtb = Kb + 8388608;                               // 16 MB

  cvt_f32_bf16<<<2048, 256, 0, stream>>>(x, xb, (M_TOT * D_MODEL) / 4);
  cvt_f32_bf16<<<1024, 256, 0, stream>>>(W, wb, (N_TOT * D_MODEL) / 4);

  dim3 ggrid(N_TOT / 128, M_TOT / 128);   // (24, 64)
  qkv_gemm<<<ggrid, 256, 0, stream>>>(xb, wb, Qb, Kb, Vtb);

  dim3 agrid(T_SEQ / 64, B_SZ * N_HEAD);  // (32, 64)
  attn_fwd<<<agrid, 256, 0, stream>>>(Qb, Kb, Vtb, out);
}

// Round 2
// 334.208 us; speedup vs baseline: 1.6981x; 1.6981x over previous
//
#include <hip/hip_runtime.h>
#include <hip/hip_bf16.h>
#include <math.h>

#define D_MODEL 1024
#define N_HEAD  16
#define HD      64
#define B_SZ    4
#define T_SEQ   2048
#define M_TOT   (B_SZ * T_SEQ)   // 8192
#define N_TOT   (3 * D_MODEL)    // 3072

typedef __bf16 bf16_t;
typedef __bf16 bf16x8 __attribute__((ext_vector_type(8)));
typedef __bf16 bf16x4 __attribute__((ext_vector_type(4)));
typedef __bf16 bf16x2 __attribute__((ext_vector_type(2)));
typedef float  f32x4  __attribute__((ext_vector_type(4)));
typedef float  f32x16 __attribute__((ext_vector_type(16)));
typedef int    i32x4  __attribute__((ext_vector_type(4)));

// softmax scale folded with log2(e): scores end up in log2 domain -> exp2f
#define Q_PRESCALE 0.18033688011112042f   // (1/8) * log2(e)

// ---------------- fp32 -> bf16 conversion (vectorized) ----------------
__global__ __launch_bounds__(256) void cvt_f32_bf16(const float* __restrict__ in,
                                                    bf16_t* __restrict__ out, int n4) {
  int i = blockIdx.x * blockDim.x + threadIdx.x;
  int stride = gridDim.x * blockDim.x;
  for (; i < n4; i += stride) {
    float4 v = ((const float4*)in)[i];
    bf16x4 o;
    o[0] = (bf16_t)v.x; o[1] = (bf16_t)v.y; o[2] = (bf16_t)v.z; o[3] = (bf16_t)v.w;
    ((bf16x4*)out)[i] = o;
  }
}

// ---------------- QKV projection GEMM (bf16 MFMA, 128x128 tile) ----------------
__global__ __launch_bounds__(256) void qkv_gemm(const bf16_t* __restrict__ xb,
                                                const bf16_t* __restrict__ wb,
                                                bf16_t* __restrict__ Q,
                                                bf16_t* __restrict__ K,
                                                bf16_t* __restrict__ Vt) {
  __shared__ alignas(16) bf16_t a_lds[128 * 32];
  __shared__ alignas(16) bf16_t b_lds[128 * 32];
  const int tid  = threadIdx.x;
  const int wave = tid >> 6;
  const int lane = tid & 63;
  const int bm = blockIdx.y * 128;
  const int bn = blockIdx.x * 128;

  f32x4 acc[4][4] = {};

  const int aRow = lane >> 2;
  const int aK8  = (lane & 3) * 8;
  const int fr   = lane & 15;
  const int fk   = (lane >> 4) * 8;
  const int wm   = (wave >> 1) * 64;
  const int wn   = (wave & 1) * 64;

  for (int kk = 0; kk < D_MODEL; kk += 32) {
#pragma unroll
    for (int c = 0; c < 2; ++c) {
      const int chunk = wave * 2 + c;
      const bf16_t* gA = &xb[(size_t)(bm + chunk * 16 + aRow) * D_MODEL + kk + aK8];
      __builtin_amdgcn_global_load_lds(
          (__attribute__((address_space(1))) void*)(void*)gA,
          (__attribute__((address_space(3))) void*)&a_lds[chunk * 512], 16, 0, 0);
      const bf16_t* gB = &wb[(size_t)(bn + chunk * 16 + aRow) * D_MODEL + kk + aK8];
      __builtin_amdgcn_global_load_lds(
          (__attribute__((address_space(1))) void*)(void*)gB,
          (__attribute__((address_space(3))) void*)&b_lds[chunk * 512], 16, 0, 0);
    }
    __syncthreads();

    bf16x8 af[4], bfr[4];
#pragma unroll
    for (int mt = 0; mt < 4; ++mt)
      af[mt] = *(const bf16x8*)&a_lds[(wm + mt * 16 + fr) * 32 + fk];
#pragma unroll
    for (int nt = 0; nt < 4; ++nt)
      bfr[nt] = *(const bf16x8*)&b_lds[(wn + nt * 16 + fr) * 32 + fk];
#pragma unroll
    for (int mt = 0; mt < 4; ++mt)
#pragma unroll
      for (int nt = 0; nt < 4; ++nt)
        acc[mt][nt] = __builtin_amdgcn_mfma_f32_16x16x32_bf16(af[mt], bfr[nt], acc[mt][nt], 0, 0, 0);
    __syncthreads();
  }

  const int cRowBase = (lane >> 4) * 4;
  const int cCol     = lane & 15;
#pragma unroll
  for (int mt = 0; mt < 4; ++mt) {
#pragma unroll
    for (int nt = 0; nt < 4; ++nt) {
      const int n   = bn + wn + nt * 16 + cCol;
      const int sec = n >> 10;            // 0=Q 1=K 2=V
      const int hn  = n & 1023;
      const int h   = hn >> 6;
      const int d   = hn & 63;
#pragma unroll
      for (int r = 0; r < 4; ++r) {
        const int m = bm + wm + mt * 16 + cRowBase + r;
        const int b = m >> 11;
        const int t = m & 2047;
        const float v = acc[mt][nt][r];
        if (sec == 0) {
          Q[((size_t)(b * N_HEAD + h) * T_SEQ + t) * HD + d] = (bf16_t)(v * Q_PRESCALE);
        } else if (sec == 1) {
          K[((size_t)(b * N_HEAD + h) * T_SEQ + t) * HD + d] = (bf16_t)v;
        } else {
          Vt[((size_t)(b * N_HEAD + h) * HD + d) * T_SEQ + t] = (bf16_t)v;
        }
      }
    }
  }
}

// ---------------- helpers ----------------
__device__ inline int pack_bf16(float lo, float hi) {
  bf16x2 v; v[0] = (bf16_t)lo; v[1] = (bf16_t)hi;
  return __builtin_bit_cast(int, v);
}
__device__ inline void permswap(int& a, int& b) {
  asm volatile("v_permlane32_swap_b32 %0, %1" : "+v"(a), "+v"(b));
}

// ---------------- causal flash attention, swapped 32x32 MFMA, no LDS ----------------
// Q [BH,T,64] prescaled by (1/8)*log2e, K [BH,T,64], Vt [BH,64,T], out fp32 [BH,T,64]
__global__ __launch_bounds__(256) void attn_fwd(const bf16_t* __restrict__ Q,
                                                const bf16_t* __restrict__ K,
                                                const bf16_t* __restrict__ Vt,
                                                float* __restrict__ out) {
  const int tid  = threadIdx.x;
  const int wave = tid >> 6;
  const int lane = tid & 63;
  const int l31  = lane & 31;
  const int hi   = lane >> 5;
  const int bh   = blockIdx.y;
  // interleaved chunk assignment balances per-block max work (triangular schedule)
  const int q0   = (blockIdx.x + 16 * wave) * 32;

  const bf16_t* Qp = Q  + (size_t)bh * T_SEQ * HD;
  const bf16_t* Kp = K  + (size_t)bh * T_SEQ * HD;
  const bf16_t* Vp = Vt + (size_t)bh * HD * T_SEQ;

  // Q fragments for this wave's 32 rows (B-operand: col=lane&31, k=(lane>>5)*8+i)
  bf16x8 qf[4];
#pragma unroll
  for (int c = 0; c < 4; ++c)
    qf[c] = *(const bf16x8*)&Qp[(size_t)(q0 + l31) * HD + c * 16 + hi * 8];

  f32x16 o0 = {}, o1 = {};
  float m_run = -INFINITY;
  float l_run = 0.f;

  for (int kv0 = 0; kv0 <= q0; kv0 += 32) {
    // S^T = K_tile x Q_tile^T : D[key][q], key = koff(r)+kv0, q = l31+q0
    f32x16 st = {};
#pragma unroll
    for (int c = 0; c < 4; ++c) {
      bf16x8 kf = *(const bf16x8*)&Kp[(size_t)(kv0 + l31) * HD + c * 16 + hi * 8];
      st = __builtin_amdgcn_mfma_f32_32x32x16_bf16(kf, qf[c], st, 0, 0, 0);
    }
    if (kv0 == q0) {   // only the diagonal tile needs causal masking
#pragma unroll
      for (int r = 0; r < 16; ++r) {
        const int koff = (r & 3) + 8 * (r >> 2) + 4 * hi;
        st[r] = (koff > l31) ? -INFINITY : st[r];
      }
    }
    // row max: per-lane tree over 16 regs + one cross-half exchange
    float pm = fmaxf(fmaxf(fmaxf(st[0], st[1]), fmaxf(st[2], st[3])),
                     fmaxf(fmaxf(st[4], st[5]), fmaxf(st[6], st[7])));
    pm = fmaxf(pm, fmaxf(fmaxf(fmaxf(st[8], st[9]), fmaxf(st[10], st[11])),
                         fmaxf(fmaxf(st[12], st[13]), fmaxf(st[14], st[15]))));
    pm = fmaxf(pm, __shfl_xor(pm, 32));

    // defer-max (T13): rescale only when the running max grows by >8 (log2 domain)
    if (__any(!(pm <= m_run + 8.f))) {
      const float m_new = fmaxf(m_run, pm);
      const float alpha = exp2f(m_run - m_new);   // first tile: exp2(-inf)=0
      m_run = m_new;
      l_run *= alpha;
#pragma unroll
      for (int r = 0; r < 16; ++r) {
        const int qr = (r & 3) + 8 * (r >> 2) + 4 * hi;
        const float av = __shfl(alpha, qr);
        o0[r] *= av; o1[r] *= av;
      }
    }

    float p[16];
#pragma unroll
    for (int r = 0; r < 16; ++r) p[r] = exp2f(st[r] - m_run);
    float s0 = (p[0] + p[1]) + (p[2] + p[3]);
    float s1 = (p[4] + p[5]) + (p[6] + p[7]);
    float s2 = (p[8] + p[9]) + (p[10] + p[11]);
    float s3 = (p[12] + p[13]) + (p[14] + p[15]);
    float ps = (s0 + s1) + (s2 + s3);
    ps += __shfl_xor(ps, 32);
    l_run += ps;

    // pack P to bf16 pairs; permlane32_swap redistributes into PV A-fragments
    int a01 = pack_bf16(p[0],  p[1]),  a23 = pack_bf16(p[2],  p[3]);
    int b01 = pack_bf16(p[4],  p[5]),  b23 = pack_bf16(p[6],  p[7]);
    int c01 = pack_bf16(p[8],  p[9]),  c23 = pack_bf16(p[10], p[11]);
    int d01 = pack_bf16(p[12], p[13]), d23 = pack_bf16(p[14], p[15]);
    permswap(a01, b01); permswap(a23, b23);
    permswap(c01, d01); permswap(c23, d23);
    i32x4 w1 = {a01, a23, b01, b23};   // keys kv0+0..15  (A-frag: row=q, k=(lane>>5)*8+i)
    i32x4 w2 = {c01, c23, d01, d23};   // keys kv0+16..31
    bf16x8 f1 = __builtin_bit_cast(bf16x8, w1);
    bf16x8 f2 = __builtin_bit_cast(bf16x8, w2);

    // O += P @ V  (V^T rows contiguous in key)
    {
      bf16x8 v0 = *(const bf16x8*)&Vp[(size_t)(0 * 32 + l31) * T_SEQ + kv0 + hi * 8];
      bf16x8 v1 = *(const bf16x8*)&Vp[(size_t)(0 * 32 + l31) * T_SEQ + kv0 + 16 + hi * 8];
      o0 = __builtin_amdgcn_mfma_f32_32x32x16_bf16(f1, v0, o0, 0, 0, 0);
      o0 = __builtin_amdgcn_mfma_f32_32x32x16_bf16(f2, v1, o0, 0, 0, 0);
      bf16x8 v2 = *(const bf16x8*)&Vp[(size_t)(1 * 32 + l31) * T_SEQ + kv0 + hi * 8];
      bf16x8 v3 = *(const bf16x8*)&Vp[(size_t)(1 * 32 + l31) * T_SEQ + kv0 + 16 + hi * 8];
      o1 = __builtin_amdgcn_mfma_f32_32x32x16_bf16(f1, v2, o1, 0, 0, 0);
      o1 = __builtin_amdgcn_mfma_f32_32x32x16_bf16(f2, v3, o1, 0, 0, 0);
    }
  }

  // epilogue: out = O / l   (O layout: row=qr, col=l31 within d-tile)
  const float linv = 1.f / l_run;
  float* op = out + (size_t)bh * T_SEQ * HD;
#pragma unroll
  for (int r = 0; r < 16; ++r) {
    const int qr = (r & 3) + 8 * (r >> 2) + 4 * hi;
    const float li = __shfl(linv, qr);
    op[(size_t)(q0 + qr) * HD + l31]      = o0[r] * li;
    op[(size_t)(q0 + qr) * HD + 32 + l31] = o1[r] * li;
  }
}

extern "C" void kernel_launch(void* const* d_in, const int* in_sizes, int n_in,
                              void* d_out, int out_size, void* d_ws, size_t ws_size,
                              hipStream_t stream) {
  const float* x = (const float*)d_in[0];
  const float* W = (const float*)d_in[1];
  float* out = (float*)d_out;

  char* ws = (char*)d_ws;
  bf16_t* xb  = (bf16_t*)(ws);
  bf16_t* wb  = (bf16_t*)(ws + 16777216);
  bf16_t* Qb  = (bf16_t*)(ws + 16777216 + 6291456);
  bf16_t* Kb  = Qb + 8388608;
  bf16_t* Vtb = Kb + 8388608;

  cvt_f32_bf16<<<2048, 256, 0, stream>>>(x, xb, (M_TOT * D_MODEL) / 4);
  cvt_f32_bf16<<<1024, 256, 0, stream>>>(W, wb, (N_TOT * D_MODEL) / 4);

  dim3 ggrid(N_TOT / 128, M_TOT / 128);   // (24, 64)
  qkv_gemm<<<ggrid, 256, 0, stream>>>(xb, wb, Qb, Kb, Vtb);

  dim3 agrid(T_SEQ / 128, B_SZ * N_HEAD); // (16, 64) — 4 indep waves/block, 32 rows each
  attn_fwd<<<agrid, 256, 0, stream>>>(Qb, Kb, Vtb, out);
}

// Round 5
// 271.562 us; speedup vs baseline: 2.0899x; 1.2307x over previous
//
#include <hip/hip_runtime.h>
#include <hip/hip_bf16.h>
#include <math.h>

#define D_MODEL 1024
#define N_HEAD  16
#define HD      64
#define B_SZ    4
#define T_SEQ   2048
#define M_TOT   (B_SZ * T_SEQ)   // 8192
#define N_TOT   (3 * D_MODEL)    // 3072

typedef __bf16 bf16_t;
typedef __bf16 bf16x8 __attribute__((ext_vector_type(8)));
typedef __bf16 bf16x4 __attribute__((ext_vector_type(4)));
typedef __bf16 bf16x2 __attribute__((ext_vector_type(2)));
typedef float  f32x4  __attribute__((ext_vector_type(4)));
typedef float  f32x16 __attribute__((ext_vector_type(16)));
typedef int    i32x4  __attribute__((ext_vector_type(4)));

// softmax scale folded with log2(e): scores end up in log2 domain -> exp2f
#define Q_PRESCALE 0.18033688011112042f   // (1/8) * log2(e)

// ---------------- fp32 -> bf16 conversion (vectorized) ----------------
__global__ __launch_bounds__(256) void cvt_f32_bf16(const float* __restrict__ in,
                                                    bf16_t* __restrict__ out, int n4) {
  int i = blockIdx.x * blockDim.x + threadIdx.x;
  int stride = gridDim.x * blockDim.x;
  for (; i < n4; i += stride) {
    float4 v = ((const float4*)in)[i];
    bf16x4 o;
    o[0] = (bf16_t)v.x; o[1] = (bf16_t)v.y; o[2] = (bf16_t)v.z; o[3] = (bf16_t)v.w;
    ((bf16x4*)out)[i] = o;
  }
}

// ---------------- QKV projection GEMM (bf16 MFMA, 128x128 tile) ----------------
__global__ __launch_bounds__(256) void qkv_gemm(const bf16_t* __restrict__ xb,
                                                const bf16_t* __restrict__ wb,
                                                bf16_t* __restrict__ Q,
                                                bf16_t* __restrict__ K,
                                                bf16_t* __restrict__ Vt) {
  __shared__ alignas(16) bf16_t a_lds[128 * 32];
  __shared__ alignas(16) bf16_t b_lds[128 * 32];
  const int tid  = threadIdx.x;
  const int wave = tid >> 6;
  const int lane = tid & 63;
  const int bm = blockIdx.y * 128;
  const int bn = blockIdx.x * 128;

  f32x4 acc[4][4] = {};

  const int aRow = lane >> 2;
  const int aK8  = (lane & 3) * 8;
  const int fr   = lane & 15;
  const int fk   = (lane >> 4) * 8;
  const int wm   = (wave >> 1) * 64;
  const int wn   = (wave & 1) * 64;

  for (int kk = 0; kk < D_MODEL; kk += 32) {
#pragma unroll
    for (int c = 0; c < 2; ++c) {
      const int chunk = wave * 2 + c;
      const bf16_t* gA = &xb[(size_t)(bm + chunk * 16 + aRow) * D_MODEL + kk + aK8];
      __builtin_amdgcn_global_load_lds(
          (__attribute__((address_space(1))) void*)(void*)gA,
          (__attribute__((address_space(3))) void*)&a_lds[chunk * 512], 16, 0, 0);
      const bf16_t* gB = &wb[(size_t)(bn + chunk * 16 + aRow) * D_MODEL + kk + aK8];
      __builtin_amdgcn_global_load_lds(
          (__attribute__((address_space(1))) void*)(void*)gB,
          (__attribute__((address_space(3))) void*)&b_lds[chunk * 512], 16, 0, 0);
    }
    __syncthreads();

    bf16x8 af[4], bfr[4];
#pragma unroll
    for (int mt = 0; mt < 4; ++mt)
      af[mt] = *(const bf16x8*)&a_lds[(wm + mt * 16 + fr) * 32 + fk];
#pragma unroll
    for (int nt = 0; nt < 4; ++nt)
      bfr[nt] = *(const bf16x8*)&b_lds[(wn + nt * 16 + fr) * 32 + fk];
#pragma unroll
    for (int mt = 0; mt < 4; ++mt)
#pragma unroll
      for (int nt = 0; nt < 4; ++nt)
        acc[mt][nt] = __builtin_amdgcn_mfma_f32_16x16x32_bf16(af[mt], bfr[nt], acc[mt][nt], 0, 0, 0);
    __syncthreads();
  }

  const int cRowBase = (lane >> 4) * 4;
  const int cCol     = lane & 15;
#pragma unroll
  for (int mt = 0; mt < 4; ++mt) {
#pragma unroll
    for (int nt = 0; nt < 4; ++nt) {
      const int n   = bn + wn + nt * 16 + cCol;
      const int sec = n >> 10;            // 0=Q 1=K 2=V
      const int hn  = n & 1023;
      const int h   = hn >> 6;
      const int d   = hn & 63;
#pragma unroll
      for (int r = 0; r < 4; ++r) {
        const int m = bm + wm + mt * 16 + cRowBase + r;
        const int b = m >> 11;
        const int t = m & 2047;
        const float v = acc[mt][nt][r];
        if (sec == 0) {
          Q[((size_t)(b * N_HEAD + h) * T_SEQ + t) * HD + d] = (bf16_t)(v * Q_PRESCALE);
        } else if (sec == 1) {
          K[((size_t)(b * N_HEAD + h) * T_SEQ + t) * HD + d] = (bf16_t)v;
        } else {
          Vt[((size_t)(b * N_HEAD + h) * HD + d) * T_SEQ + t] = (bf16_t)v;
        }
      }
    }
  }
}

// ---------------- helpers ----------------
__device__ inline int pack_bf16(float lo, float hi) {
  bf16x2 v; v[0] = (bf16_t)lo; v[1] = (bf16_t)hi;
  return __builtin_bit_cast(int, v);
}
// P-redistribution swap: ROUND-2-PROVEN inline asm. Only ever called with
// provably-distinct SSA values (different p[] packs), so no coalescing hazard.
__device__ inline void permswap(int& a, int& b) {
  asm volatile("v_permlane32_swap_b32 %0, %1" : "+v"(a), "+v"(b));
}

__device__ inline void loadK4(bf16x8 k[4], const bf16_t* __restrict__ Kp,
                              int kv0, int l31, int hi) {
#pragma unroll
  for (int c = 0; c < 4; ++c)
    k[c] = *(const bf16x8*)&Kp[(size_t)(kv0 + l31) * HD + c * 16 + hi * 8];
}
__device__ inline void loadV4(bf16x8 v[4], const bf16_t* __restrict__ Vp,
                              int kv0, int l31, int hi) {
  v[0] = *(const bf16x8*)&Vp[(size_t)(l31) * T_SEQ + kv0 + hi * 8];
  v[1] = *(const bf16x8*)&Vp[(size_t)(l31) * T_SEQ + kv0 + 16 + hi * 8];
  v[2] = *(const bf16x8*)&Vp[(size_t)(32 + l31) * T_SEQ + kv0 + hi * 8];
  v[3] = *(const bf16x8*)&Vp[(size_t)(32 + l31) * T_SEQ + kv0 + 16 + hi * 8];
}

// ---------------- causal flash attention, swapped 32x32 MFMA, no LDS ----------------
// Q [BH,T,64] prescaled by (1/8)*log2e, K [BH,T,64], Vt [BH,64,T], out fp32 [BH,T,64]
__global__ __launch_bounds__(256) void attn_fwd(const bf16_t* __restrict__ Q,
                                                const bf16_t* __restrict__ K,
                                                const bf16_t* __restrict__ Vt,
                                                float* __restrict__ out) {
  const int tid  = threadIdx.x;
  const int wave = tid >> 6;
  const int lane = tid & 63;
  const int l31  = lane & 31;
  const int hi   = lane >> 5;
  const int bh   = blockIdx.y;
  const int bx   = blockIdx.x;   // 0..15

  // Balanced chunk set per block: {bx, 31-bx, 32+bx, 63-bx} (130 tiles/block).
  // Rotation by (bh>>4) makes the 4 blocks co-resident on a CU (which share bx
  // and differ in bh by 16) put DIFFERENT set positions on each SIMD ->
  // every SIMD gets exactly 130 tiles.
  const int pos = (wave + (bh >> 4)) & 3;
  const int chunk = (pos == 0) ? bx : (pos == 1) ? (31 - bx)
                   : (pos == 2) ? (32 + bx) : (63 - bx);
  const int q0 = chunk * 32;

  const bf16_t* Qp = Q  + (size_t)bh * T_SEQ * HD;
  const bf16_t* Kp = K  + (size_t)bh * T_SEQ * HD;
  const bf16_t* Vp = Vt + (size_t)bh * HD * T_SEQ;

  // Q fragments for this wave's 32 rows (B-operand: col=lane&31, k=(lane>>5)*8+i)
  bf16x8 qf[4];
#pragma unroll
  for (int c = 0; c < 4; ++c)
    qf[c] = *(const bf16x8*)&Qp[(size_t)(q0 + l31) * HD + c * 16 + hi * 8];

  f32x16 o0 = {}, o1 = {};
  float m_run = -INFINITY;
  float l_run = 0.f;

  bf16x8 kA[4], vA[4];
  loadK4(kA, Kp, 0, l31, hi);

  for (int kv0 = 0; kv0 <= q0; kv0 += 32) {
    // V for THIS tile: issue now, consumed after softmax (~250 cyc of hiding)
    loadV4(vA, Vp, kv0, l31, hi);

    // S^T = K_tile x Q_tile^T : D[key][q], key = koff(r)+kv0, q = l31+q0
    f32x16 st = {};
    __builtin_amdgcn_s_setprio(1);
#pragma unroll
    for (int c = 0; c < 4; ++c)
      st = __builtin_amdgcn_mfma_f32_32x32x16_bf16(kA[c], qf[c], st, 0, 0, 0);
    __builtin_amdgcn_s_setprio(0);

    // prefetch K for NEXT tile (regalloc double-buffers; hides under softmax+PV)
    const int nxt = (kv0 + 32 <= q0) ? kv0 + 32 : kv0;
    loadK4(kA, Kp, nxt, l31, hi);

    if (kv0 == q0) {   // only the diagonal tile needs causal masking
#pragma unroll
      for (int r = 0; r < 16; ++r) {
        const int koff = (r & 3) + 8 * (r >> 2) + 4 * hi;
        st[r] = (koff > l31) ? -INFINITY : st[r];
      }
    }
    // row max: per-lane tree over 16 regs + one cross-half exchange
    // (__shfl_xor(.,32) — ROUND-2-PROVEN)
    float pm = fmaxf(fmaxf(fmaxf(st[0], st[1]), fmaxf(st[2], st[3])),
                     fmaxf(fmaxf(st[4], st[5]), fmaxf(st[6], st[7])));
    pm = fmaxf(pm, fmaxf(fmaxf(fmaxf(st[8], st[9]), fmaxf(st[10], st[11])),
                         fmaxf(fmaxf(st[12], st[13]), fmaxf(st[14], st[15]))));
    pm = fmaxf(pm, __shfl_xor(pm, 32));

    // defer-max (T13): rescale only when the running max grows by >8 (log2 domain)
    if (__any(!(pm <= m_run + 8.f))) {
      const float m_new = fmaxf(m_run, pm);
      const float alpha = exp2f(m_run - m_new);   // first tile: exp2(-inf)=0
      m_run = m_new;
      l_run *= alpha;
#pragma unroll
      for (int r = 0; r < 16; ++r) {
        const int qr = (r & 3) + 8 * (r >> 2) + 4 * hi;
        const float av = __shfl(alpha, qr);
        o0[r] *= av; o1[r] *= av;
      }
    }

    float p[16];
#pragma unroll
    for (int r = 0; r < 16; ++r) p[r] = exp2f(st[r] - m_run);
    float s0 = (p[0] + p[1]) + (p[2] + p[3]);
    float s1 = (p[4] + p[5]) + (p[6] + p[7]);
    float s2 = (p[8] + p[9]) + (p[10] + p[11]);
    float s3 = (p[12] + p[13]) + (p[14] + p[15]);
    float ps = (s0 + s1) + (s2 + s3);
    ps += __shfl_xor(ps, 32);
    l_run += ps;

    // pack P to bf16 pairs; permlane32_swap redistributes into PV A-fragments
    int a01 = pack_bf16(p[0],  p[1]),  a23 = pack_bf16(p[2],  p[3]);
    int b01 = pack_bf16(p[4],  p[5]),  b23 = pack_bf16(p[6],  p[7]);
    int c01 = pack_bf16(p[8],  p[9]),  c23 = pack_bf16(p[10], p[11]);
    int d01 = pack_bf16(p[12], p[13]), d23 = pack_bf16(p[14], p[15]);
    permswap(a01, b01); permswap(a23, b23);
    permswap(c01, d01); permswap(c23, d23);
    i32x4 w1 = {a01, a23, b01, b23};   // keys kv0+0..15
    i32x4 w2 = {c01, c23, d01, d23};   // keys kv0+16..31
    bf16x8 f1 = __builtin_bit_cast(bf16x8, w1);
    bf16x8 f2 = __builtin_bit_cast(bf16x8, w2);

    // O += P @ V  (V^T rows contiguous in key)
    __builtin_amdgcn_s_setprio(1);
    o0 = __builtin_amdgcn_mfma_f32_32x32x16_bf16(f1, vA[0], o0, 0, 0, 0);
    o0 = __builtin_amdgcn_mfma_f32_32x32x16_bf16(f2, vA[1], o0, 0, 0, 0);
    o1 = __builtin_amdgcn_mfma_f32_32x32x16_bf16(f1, vA[2], o1, 0, 0, 0);
    o1 = __builtin_amdgcn_mfma_f32_32x32x16_bf16(f2, vA[3], o1, 0, 0, 0);
    __builtin_amdgcn_s_setprio(0);
  }

  // epilogue: out = O / l   (O layout: row=qr, col=l31 within d-tile)
  const float linv = 1.f / l_run;
  float* op = out + (size_t)bh * T_SEQ * HD;
#pragma unroll
  for (int r = 0; r < 16; ++r) {
    const int qr = (r & 3) + 8 * (r >> 2) + 4 * hi;
    const float li = __shfl(linv, qr);
    op[(size_t)(q0 + qr) * HD + l31]      = o0[r] * li;
    op[(size_t)(q0 + qr) * HD + 32 + l31] = o1[r] * li;
  }
}

extern "C" void kernel_launch(void* const* d_in, const int* in_sizes, int n_in,
                              void* d_out, int out_size, void* d_ws, size_t ws_size,
                              hipStream_t stream) {
  const float* x = (const float*)d_in[0];
  const float* W = (const float*)d_in[1];
  float* out = (float*)d_out;

  char* ws = (char*)d_ws;
  bf16_t* xb  = (bf16_t*)(ws);
  bf16_t* wb  = (bf16_t*)(ws + 16777216);
  bf16_t* Qb  = (bf16_t*)(ws + 16777216 + 6291456);
  bf16_t* Kb  = Qb + 8388608;
  bf16_t* Vtb = Kb + 8388608;

  cvt_f32_bf16<<<2048, 256, 0, stream>>>(x, xb, (M_TOT * D_MODEL) / 4);
  cvt_f32_bf16<<<1024, 256, 0, stream>>>(W, wb, (N_TOT * D_MODEL) / 4);

  dim3 ggrid(N_TOT / 128, M_TOT / 128);   // (24, 64)
  qkv_gemm<<<ggrid, 256, 0, stream>>>(xb, wb, Qb, Kb, Vtb);

  dim3 agrid(T_SEQ / 128, B_SZ * N_HEAD); // (16, 64)
  attn_fwd<<<agrid, 256, 0, stream>>>(Qb, Kb, Vtb, out);
}

// Round 6
// 268.866 us; speedup vs baseline: 2.1108x; 1.0100x over previous
//
#include <hip/hip_runtime.h>
#include <hip/hip_bf16.h>
#include <math.h>

#define D_MODEL 1024
#define N_HEAD  16
#define HD      64
#define B_SZ    4
#define T_SEQ   2048
#define M_TOT   (B_SZ * T_SEQ)   // 8192
#define N_TOT   (3 * D_MODEL)    // 3072

typedef __bf16 bf16_t;
typedef __bf16 bf16x8 __attribute__((ext_vector_type(8)));
typedef __bf16 bf16x4 __attribute__((ext_vector_type(4)));
typedef __bf16 bf16x2 __attribute__((ext_vector_type(2)));
typedef float  f32x4  __attribute__((ext_vector_type(4)));
typedef float  f32x16 __attribute__((ext_vector_type(16)));
typedef int    i32x4  __attribute__((ext_vector_type(4)));

// softmax scale folded with log2(e): scores end up in log2 domain -> exp2f
#define Q_PRESCALE 0.18033688011112042f   // (1/8) * log2(e)

// ---------------- fp32 -> bf16 conversion (vectorized) ----------------
__global__ __launch_bounds__(256) void cvt_f32_bf16(const float* __restrict__ in,
                                                    bf16_t* __restrict__ out, int n4) {
  int i = blockIdx.x * blockDim.x + threadIdx.x;
  int stride = gridDim.x * blockDim.x;
  for (; i < n4; i += stride) {
    float4 v = ((const float4*)in)[i];
    bf16x4 o;
    o[0] = (bf16_t)v.x; o[1] = (bf16_t)v.y; o[2] = (bf16_t)v.z; o[3] = (bf16_t)v.w;
    ((bf16x4*)out)[i] = o;
  }
}

// ---------------- QKV projection GEMM (bf16 MFMA, 128x128 tile) ----------------
__global__ __launch_bounds__(256) void qkv_gemm(const bf16_t* __restrict__ xb,
                                                const bf16_t* __restrict__ wb,
                                                bf16_t* __restrict__ Q,
                                                bf16_t* __restrict__ K,
                                                bf16_t* __restrict__ Vt) {
  __shared__ alignas(16) bf16_t a_lds[128 * 32];
  __shared__ alignas(16) bf16_t b_lds[128 * 32];
  const int tid  = threadIdx.x;
  const int wave = tid >> 6;
  const int lane = tid & 63;
  const int bm = blockIdx.y * 128;
  const int bn = blockIdx.x * 128;

  f32x4 acc[4][4] = {};

  const int aRow = lane >> 2;
  const int aK8  = (lane & 3) * 8;
  const int fr   = lane & 15;
  const int fk   = (lane >> 4) * 8;
  const int wm   = (wave >> 1) * 64;
  const int wn   = (wave & 1) * 64;

  for (int kk = 0; kk < D_MODEL; kk += 32) {
#pragma unroll
    for (int c = 0; c < 2; ++c) {
      const int chunk = wave * 2 + c;
      const bf16_t* gA = &xb[(size_t)(bm + chunk * 16 + aRow) * D_MODEL + kk + aK8];
      __builtin_amdgcn_global_load_lds(
          (__attribute__((address_space(1))) void*)(void*)gA,
          (__attribute__((address_space(3))) void*)&a_lds[chunk * 512], 16, 0, 0);
      const bf16_t* gB = &wb[(size_t)(bn + chunk * 16 + aRow) * D_MODEL + kk + aK8];
      __builtin_amdgcn_global_load_lds(
          (__attribute__((address_space(1))) void*)(void*)gB,
          (__attribute__((address_space(3))) void*)&b_lds[chunk * 512], 16, 0, 0);
    }
    __syncthreads();

    bf16x8 af[4], bfr[4];
#pragma unroll
    for (int mt = 0; mt < 4; ++mt)
      af[mt] = *(const bf16x8*)&a_lds[(wm + mt * 16 + fr) * 32 + fk];
#pragma unroll
    for (int nt = 0; nt < 4; ++nt)
      bfr[nt] = *(const bf16x8*)&b_lds[(wn + nt * 16 + fr) * 32 + fk];
#pragma unroll
    for (int mt = 0; mt < 4; ++mt)
#pragma unroll
      for (int nt = 0; nt < 4; ++nt)
        acc[mt][nt] = __builtin_amdgcn_mfma_f32_16x16x32_bf16(af[mt], bfr[nt], acc[mt][nt], 0, 0, 0);
    __syncthreads();
  }

  const int cRowBase = (lane >> 4) * 4;
  const int cCol     = lane & 15;
#pragma unroll
  for (int mt = 0; mt < 4; ++mt) {
#pragma unroll
    for (int nt = 0; nt < 4; ++nt) {
      const int n   = bn + wn + nt * 16 + cCol;
      const int sec = n >> 10;            // 0=Q 1=K 2=V
      const int hn  = n & 1023;
      const int h   = hn >> 6;
      const int d   = hn & 63;
#pragma unroll
      for (int r = 0; r < 4; ++r) {
        const int m = bm + wm + mt * 16 + cRowBase + r;
        const int b = m >> 11;
        const int t = m & 2047;
        const float v = acc[mt][nt][r];
        if (sec == 0) {
          Q[((size_t)(b * N_HEAD + h) * T_SEQ + t) * HD + d] = (bf16_t)(v * Q_PRESCALE);
        } else if (sec == 1) {
          K[((size_t)(b * N_HEAD + h) * T_SEQ + t) * HD + d] = (bf16_t)v;
        } else {
          Vt[((size_t)(b * N_HEAD + h) * HD + d) * T_SEQ + t] = (bf16_t)v;
        }
      }
    }
  }
}

// ---------------- helpers ----------------
__device__ inline int pack_bf16(float lo, float hi) {
  bf16x2 v; v[0] = (bf16_t)lo; v[1] = (bf16_t)hi;
  return __builtin_bit_cast(int, v);
}
// P-redistribution swap: ROUND-2-PROVEN inline asm. Only ever called with
// provably-distinct SSA values (different p[] packs), so no coalescing hazard.
__device__ inline void permswap(int& a, int& b) {
  asm volatile("v_permlane32_swap_b32 %0, %1" : "+v"(a), "+v"(b));
}

__device__ inline void loadK4(bf16x8 k[4], const bf16_t* __restrict__ Kp,
                              int kv0, int l31, int hi) {
#pragma unroll
  for (int c = 0; c < 4; ++c)
    k[c] = *(const bf16x8*)&Kp[(size_t)(kv0 + l31) * HD + c * 16 + hi * 8];
}
__device__ inline void loadV4(bf16x8 v[4], const bf16_t* __restrict__ Vp,
                              int kv0, int l31, int hi) {
  v[0] = *(const bf16x8*)&Vp[(size_t)(l31) * T_SEQ + kv0 + hi * 8];
  v[1] = *(const bf16x8*)&Vp[(size_t)(l31) * T_SEQ + kv0 + 16 + hi * 8];
  v[2] = *(const bf16x8*)&Vp[(size_t)(32 + l31) * T_SEQ + kv0 + hi * 8];
  v[3] = *(const bf16x8*)&Vp[(size_t)(32 + l31) * T_SEQ + kv0 + 16 + hi * 8];
}

// ---------------- causal flash attention, swapped 32x32 MFMA, no LDS ----------------
// Q [BH,T,64] prescaled by (1/8)*log2e, K [BH,T,64], Vt [BH,64,T], out fp32 [BH,T,64]
//
// Softmax bookkeeping: each lane (row q=l31, half hi) tracks m_run and a
// PARTIAL l_run over its own 16 keys/tile. m_run is kept identical across the
// two half-lanes of a row: it only changes inside the rescale branch, where the
// cross-half max exchange happens. Steady-state tiles have NO cross-lane ops
// except the 4 permswaps (VALU). l halves combine once in the epilogue.
__global__ __launch_bounds__(256) void attn_fwd(const bf16_t* __restrict__ Q,
                                                const bf16_t* __restrict__ K,
                                                const bf16_t* __restrict__ Vt,
                                                float* __restrict__ out) {
  const int tid  = threadIdx.x;
  const int wave = tid >> 6;
  const int lane = tid & 63;
  const int l31  = lane & 31;
  const int hi   = lane >> 5;
  const int bh   = blockIdx.y;
  const int bx   = blockIdx.x;   // 0..15

  // Balanced chunk set per block: {bx, 31-bx, 32+bx, 63-bx} (130 tiles/block).
  // Rotation by (bh>>4): co-resident blocks put different set positions on
  // each SIMD -> every SIMD gets exactly 130 tiles.
  const int pos = (wave + (bh >> 4)) & 3;
  const int chunk = (pos == 0) ? bx : (pos == 1) ? (31 - bx)
                   : (pos == 2) ? (32 + bx) : (63 - bx);
  const int q0 = chunk * 32;

  const bf16_t* Qp = Q  + (size_t)bh * T_SEQ * HD;
  const bf16_t* Kp = K  + (size_t)bh * T_SEQ * HD;
  const bf16_t* Vp = Vt + (size_t)bh * HD * T_SEQ;

  // Q fragments for this wave's 32 rows (B-operand: col=lane&31, k=(lane>>5)*8+i)
  bf16x8 qf[4];
#pragma unroll
  for (int c = 0; c < 4; ++c)
    qf[c] = *(const bf16x8*)&Qp[(size_t)(q0 + l31) * HD + c * 16 + hi * 8];

  f32x16 o0 = {}, o1 = {};
  float m_run = -INFINITY;
  float l_run = 0.f;          // per-lane HALF-row partial sum

  bf16x8 kA[4], vA[4];
  loadK4(kA, Kp, 0, l31, hi);

  for (int kv0 = 0; kv0 <= q0; kv0 += 32) {
    // V for THIS tile: issue now, consumed after softmax (~250 cyc of hiding)
    loadV4(vA, Vp, kv0, l31, hi);

    // S^T = K_tile x Q_tile^T : D[key][q], key = koff(r)+kv0, q = l31+q0
    f32x16 st = {};
    __builtin_amdgcn_s_setprio(1);
#pragma unroll
    for (int c = 0; c < 4; ++c)
      st = __builtin_amdgcn_mfma_f32_32x32x16_bf16(kA[c], qf[c], st, 0, 0, 0);
    __builtin_amdgcn_s_setprio(0);

    // prefetch K for NEXT tile (regalloc double-buffers; hides under softmax+PV)
    const int nxt = (kv0 + 32 <= q0) ? kv0 + 32 : kv0;
    loadK4(kA, Kp, nxt, l31, hi);

    if (kv0 == q0) {   // only the diagonal tile needs causal masking
#pragma unroll
      for (int r = 0; r < 16; ++r) {
        const int koff = (r & 3) + 8 * (r >> 2) + 4 * hi;
        st[r] = (koff > l31) ? -INFINITY : st[r];
      }
    }
    // per-lane local max over this lane's 16 scores (VALU tree, no cross-lane)
    float pm = fmaxf(fmaxf(fmaxf(st[0], st[1]), fmaxf(st[2], st[3])),
                     fmaxf(fmaxf(st[4], st[5]), fmaxf(st[6], st[7])));
    pm = fmaxf(pm, fmaxf(fmaxf(fmaxf(st[8], st[9]), fmaxf(st[10], st[11])),
                         fmaxf(fmaxf(st[12], st[13]), fmaxf(st[14], st[15]))));

    // defer-max (T13): rescale only when the local max grows past m_run+8.
    // Cross-half max exchange lives ONLY here (first tile always triggers,
    // establishing row-consistent m_run across the two half-lanes).
    if (__any(!(pm <= m_run + 8.f))) {
      const float pm_full = fmaxf(pm, __shfl_xor(pm, 32));
      const float m_new = fmaxf(m_run, pm_full);
      const float alpha = exp2f(m_run - m_new);   // first tile: exp2(-inf)=0
      m_run = m_new;
      l_run *= alpha;
#pragma unroll
      for (int r = 0; r < 16; ++r) {
        const int qr = (r & 3) + 8 * (r >> 2) + 4 * hi;
        const float av = __shfl(alpha, qr);
        o0[r] *= av; o1[r] *= av;
      }
    }

    float p[16];
#pragma unroll
    for (int r = 0; r < 16; ++r) p[r] = exp2f(st[r] - m_run);
    float s0 = (p[0] + p[1]) + (p[2] + p[3]);
    float s1 = (p[4] + p[5]) + (p[6] + p[7]);
    float s2 = (p[8] + p[9]) + (p[10] + p[11]);
    float s3 = (p[12] + p[13]) + (p[14] + p[15]);
    l_run += (s0 + s1) + (s2 + s3);   // per-lane partial; halves combined at end

    // pack P to bf16 pairs; permlane32_swap redistributes into PV A-fragments
    int a01 = pack_bf16(p[0],  p[1]),  a23 = pack_bf16(p[2],  p[3]);
    int b01 = pack_bf16(p[4],  p[5]),  b23 = pack_bf16(p[6],  p[7]);
    int c01 = pack_bf16(p[8],  p[9]),  c23 = pack_bf16(p[10], p[11]);
    int d01 = pack_bf16(p[12], p[13]), d23 = pack_bf16(p[14], p[15]);
    permswap(a01, b01); permswap(a23, b23);
    permswap(c01, d01); permswap(c23, d23);
    i32x4 w1 = {a01, a23, b01, b23};   // keys kv0+0..15
    i32x4 w2 = {c01, c23, d01, d23};   // keys kv0+16..31
    bf16x8 f1 = __builtin_bit_cast(bf16x8, w1);
    bf16x8 f2 = __builtin_bit_cast(bf16x8, w2);

    // O += P @ V  (V^T rows contiguous in key)
    __builtin_amdgcn_s_setprio(1);
    o0 = __builtin_amdgcn_mfma_f32_32x32x16_bf16(f1, vA[0], o0, 0, 0, 0);
    o0 = __builtin_amdgcn_mfma_f32_32x32x16_bf16(f2, vA[1], o0, 0, 0, 0);
    o1 = __builtin_amdgcn_mfma_f32_32x32x16_bf16(f1, vA[2], o1, 0, 0, 0);
    o1 = __builtin_amdgcn_mfma_f32_32x32x16_bf16(f2, vA[3], o1, 0, 0, 0);
    __builtin_amdgcn_s_setprio(0);
  }

  // epilogue: combine l halves (one shfl per kernel), out = O / l
  const float l_tot = l_run + __shfl_xor(l_run, 32);
  const float linv = 1.f / l_tot;
  float* op = out + (size_t)bh * T_SEQ * HD;
#pragma unroll
  for (int r = 0; r < 16; ++r) {
    const int qr = (r & 3) + 8 * (r >> 2) + 4 * hi;
    const float li = __shfl(linv, qr);
    op[(size_t)(q0 + qr) * HD + l31]      = o0[r] * li;
    op[(size_t)(q0 + qr) * HD + 32 + l31] = o1[r] * li;
  }
}

extern "C" void kernel_launch(void* const* d_in, const int* in_sizes, int n_in,
                              void* d_out, int out_size, void* d_ws, size_t ws_size,
                              hipStream_t stream) {
  const float* x = (const float*)d_in[0];
  const float* W = (const float*)d_in[1];
  float* out = (float*)d_out;

  char* ws = (char*)d_ws;
  bf16_t* xb  = (bf16_t*)(ws);
  bf16_t* wb  = (bf16_t*)(ws + 16777216);
  bf16_t* Qb  = (bf16_t*)(ws + 16777216 + 6291456);
  bf16_t* Kb  = Qb + 8388608;
  bf16_t* Vtb = Kb + 8388608;

  cvt_f32_bf16<<<2048, 256, 0, stream>>>(x, xb, (M_TOT * D_MODEL) / 4);
  cvt_f32_bf16<<<1024, 256, 0, stream>>>(W, wb, (N_TOT * D_MODEL) / 4);

  dim3 ggrid(N_TOT / 128, M_TOT / 128);   // (24, 64)
  qkv_gemm<<<ggrid, 256, 0, stream>>>(xb, wb, Qb, Kb, Vtb);

  dim3 agrid(T_SEQ / 128, B_SZ * N_HEAD); // (16, 64)
  attn_fwd<<<agrid, 256, 0, stream>>>(Qb, Kb, Vtb, out);
}

// Round 7
// 242.293 us; speedup vs baseline: 2.3423x; 1.1097x over previous
//
#include <hip/hip_runtime.h>
#include <hip/hip_bf16.h>
#include <math.h>

#define D_MODEL 1024
#define N_HEAD  16
#define HD      64
#define B_SZ    4
#define T_SEQ   2048
#define M_TOT   (B_SZ * T_SEQ)   // 8192
#define N_TOT   (3 * D_MODEL)    // 3072

typedef __bf16 bf16_t;
typedef __bf16 bf16x8 __attribute__((ext_vector_type(8)));
typedef __bf16 bf16x4 __attribute__((ext_vector_type(4)));
typedef __bf16 bf16x2 __attribute__((ext_vector_type(2)));
typedef float  f32x4  __attribute__((ext_vector_type(4)));
typedef float  f32x16 __attribute__((ext_vector_type(16)));
typedef int    i32x4  __attribute__((ext_vector_type(4)));

// softmax scale folded with log2(e): scores end up in log2 domain -> exp2f
#define Q_PRESCALE 0.18033688011112042f   // (1/8) * log2(e)

// ---------------- fp32 -> bf16 conversion (vectorized) ----------------
__global__ __launch_bounds__(256) void cvt_f32_bf16(const float* __restrict__ in,
                                                    bf16_t* __restrict__ out, int n4) {
  int i = blockIdx.x * blockDim.x + threadIdx.x;
  int stride = gridDim.x * blockDim.x;
  for (; i < n4; i += stride) {
    float4 v = ((const float4*)in)[i];
    bf16x4 o;
    o[0] = (bf16_t)v.x; o[1] = (bf16_t)v.y; o[2] = (bf16_t)v.z; o[3] = (bf16_t)v.w;
    ((bf16x4*)out)[i] = o;
  }
}

// ---------------- QKV projection GEMM (bf16 MFMA, 128x128 tile) ----------------
__global__ __launch_bounds__(256) void qkv_gemm(const bf16_t* __restrict__ xb,
                                                const bf16_t* __restrict__ wb,
                                                bf16_t* __restrict__ Q,
                                                bf16_t* __restrict__ K,
                                                bf16_t* __restrict__ Vt) {
  __shared__ alignas(16) bf16_t a_lds[128 * 32];
  __shared__ alignas(16) bf16_t b_lds[128 * 32];
  const int tid  = threadIdx.x;
  const int wave = tid >> 6;
  const int lane = tid & 63;
  const int bm = blockIdx.y * 128;
  const int bn = blockIdx.x * 128;

  f32x4 acc[4][4] = {};

  const int aRow = lane >> 2;
  const int aK8  = (lane & 3) * 8;
  const int fr   = lane & 15;
  const int fk   = (lane >> 4) * 8;
  const int wm   = (wave >> 1) * 64;
  const int wn   = (wave & 1) * 64;

  for (int kk = 0; kk < D_MODEL; kk += 32) {
#pragma unroll
    for (int c = 0; c < 2; ++c) {
      const int chunk = wave * 2 + c;
      const bf16_t* gA = &xb[(size_t)(bm + chunk * 16 + aRow) * D_MODEL + kk + aK8];
      __builtin_amdgcn_global_load_lds(
          (__attribute__((address_space(1))) void*)(void*)gA,
          (__attribute__((address_space(3))) void*)&a_lds[chunk * 512], 16, 0, 0);
      const bf16_t* gB = &wb[(size_t)(bn + chunk * 16 + aRow) * D_MODEL + kk + aK8];
      __builtin_amdgcn_global_load_lds(
          (__attribute__((address_space(1))) void*)(void*)gB,
          (__attribute__((address_space(3))) void*)&b_lds[chunk * 512], 16, 0, 0);
    }
    __syncthreads();

    bf16x8 af[4], bfr[4];
#pragma unroll
    for (int mt = 0; mt < 4; ++mt)
      af[mt] = *(const bf16x8*)&a_lds[(wm + mt * 16 + fr) * 32 + fk];
#pragma unroll
    for (int nt = 0; nt < 4; ++nt)
      bfr[nt] = *(const bf16x8*)&b_lds[(wn + nt * 16 + fr) * 32 + fk];
#pragma unroll
    for (int mt = 0; mt < 4; ++mt)
#pragma unroll
      for (int nt = 0; nt < 4; ++nt)
        acc[mt][nt] = __builtin_amdgcn_mfma_f32_16x16x32_bf16(af[mt], bfr[nt], acc[mt][nt], 0, 0, 0);
    __syncthreads();
  }

  const int cRowBase = (lane >> 4) * 4;
  const int cCol     = lane & 15;
#pragma unroll
  for (int mt = 0; mt < 4; ++mt) {
#pragma unroll
    for (int nt = 0; nt < 4; ++nt) {
      const int n   = bn + wn + nt * 16 + cCol;
      const int sec = n >> 10;            // 0=Q 1=K 2=V
      const int hn  = n & 1023;
      const int h   = hn >> 6;
      const int d   = hn & 63;
#pragma unroll
      for (int r = 0; r < 4; ++r) {
        const int m = bm + wm + mt * 16 + cRowBase + r;
        const int b = m >> 11;
        const int t = m & 2047;
        const float v = acc[mt][nt][r];
        if (sec == 0) {
          Q[((size_t)(b * N_HEAD + h) * T_SEQ + t) * HD + d] = (bf16_t)(v * Q_PRESCALE);
        } else if (sec == 1) {
          K[((size_t)(b * N_HEAD + h) * T_SEQ + t) * HD + d] = (bf16_t)v;
        } else {
          Vt[((size_t)(b * N_HEAD + h) * HD + d) * T_SEQ + t] = (bf16_t)v;
        }
      }
    }
  }
}

// ---------------- helpers ----------------
__device__ inline int pack_bf16(float lo, float hi) {
  bf16x2 v; v[0] = (bf16_t)lo; v[1] = (bf16_t)hi;
  return __builtin_bit_cast(int, v);
}
// P-redistribution swap: ROUND-2-PROVEN inline asm. Only ever called with
// provably-distinct SSA values (different p[] packs), so no coalescing hazard.
__device__ inline void permswap(int& a, int& b) {
  asm volatile("v_permlane32_swap_b32 %0, %1" : "+v"(a), "+v"(b));
}

__device__ inline void loadK4(bf16x8 k[4], const bf16_t* __restrict__ Kp,
                              int kv0, int l31, int hi) {
#pragma unroll
  for (int c = 0; c < 4; ++c)
    k[c] = *(const bf16x8*)&Kp[(size_t)(kv0 + l31) * HD + c * 16 + hi * 8];
}
__device__ inline void loadV4(bf16x8 v[4], const bf16_t* __restrict__ Vp,
                              int kv0, int l31, int hi) {
  v[0] = *(const bf16x8*)&Vp[(size_t)(l31) * T_SEQ + kv0 + hi * 8];
  v[1] = *(const bf16x8*)&Vp[(size_t)(l31) * T_SEQ + kv0 + 16 + hi * 8];
  v[2] = *(const bf16x8*)&Vp[(size_t)(32 + l31) * T_SEQ + kv0 + hi * 8];
  v[3] = *(const bf16x8*)&Vp[(size_t)(32 + l31) * T_SEQ + kv0 + 16 + hi * 8];
}

// ---------------- causal flash attention, swapped 32x32 MFMA, no LDS ----------------
// Q [BH,T,64] prescaled by (1/8)*log2e, K [BH,T,64], Vt [BH,64,T], out fp32 [BH,T,64]
//
// Work distribution: each wave processes TWO complementary chunks c and 63-c:
// (c+1) + (64-c) = 65 tiles for EVERY wave -> perfectly uniform waves with no
// assumptions about block->CU placement (round-6 lesson: per-block aggregate
// balance left single long waves exposing the full dependency chain).
__global__ __launch_bounds__(256) void attn_fwd(const bf16_t* __restrict__ Q,
                                                const bf16_t* __restrict__ K,
                                                const bf16_t* __restrict__ Vt,
                                                float* __restrict__ out) {
  const int tid  = threadIdx.x;
  const int wave = tid >> 6;
  const int lane = tid & 63;
  const int l31  = lane & 31;
  const int hi   = lane >> 5;
  const int bh   = blockIdx.y;
  const int c_lo = blockIdx.x * 4 + wave;   // 0..31

  const bf16_t* Qp = Q  + (size_t)bh * T_SEQ * HD;
  const bf16_t* Kp = K  + (size_t)bh * T_SEQ * HD;
  const bf16_t* Vp = Vt + (size_t)bh * HD * T_SEQ;
  float* op = out + (size_t)bh * T_SEQ * HD;

  for (int half = 0; half < 2; ++half) {
    const int chunk = half ? (63 - c_lo) : c_lo;
    const int q0 = chunk * 32;

    // Q fragments (B-operand: col=lane&31, k=(lane>>5)*8+i)
    bf16x8 qf[4];
#pragma unroll
    for (int c = 0; c < 4; ++c)
      qf[c] = *(const bf16x8*)&Qp[(size_t)(q0 + l31) * HD + c * 16 + hi * 8];

    f32x16 o0 = {}, o1 = {};
    float m_run = -INFINITY;
    float l_run = 0.f;          // per-lane HALF-row partial sum

    bf16x8 kA[4], vA[4];
    loadK4(kA, Kp, 0, l31, hi);

    for (int kv0 = 0; kv0 <= q0; kv0 += 32) {
      // V for THIS tile: issue now, consumed after softmax
      loadV4(vA, Vp, kv0, l31, hi);

      // S^T = K_tile x Q_tile^T : D[key][q], key = koff(r)+kv0, q = l31+q0
      f32x16 st = {};
      __builtin_amdgcn_s_setprio(1);
#pragma unroll
      for (int c = 0; c < 4; ++c)
        st = __builtin_amdgcn_mfma_f32_32x32x16_bf16(kA[c], qf[c], st, 0, 0, 0);
      __builtin_amdgcn_s_setprio(0);

      // prefetch K for NEXT tile (regalloc double-buffers; hides under softmax+PV)
      const int nxt = (kv0 + 32 <= q0) ? kv0 + 32 : kv0;
      loadK4(kA, Kp, nxt, l31, hi);

      if (kv0 == q0) {   // only the diagonal tile needs causal masking
#pragma unroll
        for (int r = 0; r < 16; ++r) {
          const int koff = (r & 3) + 8 * (r >> 2) + 4 * hi;
          st[r] = (koff > l31) ? -INFINITY : st[r];
        }
      }
      // per-lane local max over this lane's 16 scores (VALU tree, no cross-lane)
      float pm = fmaxf(fmaxf(fmaxf(st[0], st[1]), fmaxf(st[2], st[3])),
                       fmaxf(fmaxf(st[4], st[5]), fmaxf(st[6], st[7])));
      pm = fmaxf(pm, fmaxf(fmaxf(fmaxf(st[8], st[9]), fmaxf(st[10], st[11])),
                           fmaxf(fmaxf(st[12], st[13]), fmaxf(st[14], st[15]))));

      // defer-max (T13): rescale only when the local max grows past m_run+8.
      // Cross-half max exchange lives ONLY here (first tile always triggers,
      // establishing row-consistent m_run across the two half-lanes).
      if (__any(!(pm <= m_run + 8.f))) {
        const float pm_full = fmaxf(pm, __shfl_xor(pm, 32));
        const float m_new = fmaxf(m_run, pm_full);
        const float alpha = exp2f(m_run - m_new);   // first tile: exp2(-inf)=0
        m_run = m_new;
        l_run *= alpha;
#pragma unroll
        for (int r = 0; r < 16; ++r) {
          const int qr = (r & 3) + 8 * (r >> 2) + 4 * hi;
          const float av = __shfl(alpha, qr);
          o0[r] *= av; o1[r] *= av;
        }
      }

      float p[16];
#pragma unroll
      for (int r = 0; r < 16; ++r) p[r] = exp2f(st[r] - m_run);
      float s0 = (p[0] + p[1]) + (p[2] + p[3]);
      float s1 = (p[4] + p[5]) + (p[6] + p[7]);
      float s2 = (p[8] + p[9]) + (p[10] + p[11]);
      float s3 = (p[12] + p[13]) + (p[14] + p[15]);
      l_run += (s0 + s1) + (s2 + s3);   // per-lane partial; halves combined at end

      // pack P to bf16 pairs; permlane32_swap redistributes into PV A-fragments
      int a01 = pack_bf16(p[0],  p[1]),  a23 = pack_bf16(p[2],  p[3]);
      int b01 = pack_bf16(p[4],  p[5]),  b23 = pack_bf16(p[6],  p[7]);
      int c01 = pack_bf16(p[8],  p[9]),  c23 = pack_bf16(p[10], p[11]);
      int d01 = pack_bf16(p[12], p[13]), d23 = pack_bf16(p[14], p[15]);
      permswap(a01, b01); permswap(a23, b23);
      permswap(c01, d01); permswap(c23, d23);
      i32x4 w1 = {a01, a23, b01, b23};   // keys kv0+0..15
      i32x4 w2 = {c01, c23, d01, d23};   // keys kv0+16..31
      bf16x8 f1 = __builtin_bit_cast(bf16x8, w1);
      bf16x8 f2 = __builtin_bit_cast(bf16x8, w2);

      // O += P @ V  (V^T rows contiguous in key)
      __builtin_amdgcn_s_setprio(1);
      o0 = __builtin_amdgcn_mfma_f32_32x32x16_bf16(f1, vA[0], o0, 0, 0, 0);
      o0 = __builtin_amdgcn_mfma_f32_32x32x16_bf16(f2, vA[1], o0, 0, 0, 0);
      o1 = __builtin_amdgcn_mfma_f32_32x32x16_bf16(f1, vA[2], o1, 0, 0, 0);
      o1 = __builtin_amdgcn_mfma_f32_32x32x16_bf16(f2, vA[3], o1, 0, 0, 0);
      __builtin_amdgcn_s_setprio(0);
    }

    // epilogue: combine l halves, out = O / l
    const float l_tot = l_run + __shfl_xor(l_run, 32);
    const float linv = 1.f / l_tot;
#pragma unroll
    for (int r = 0; r < 16; ++r) {
      const int qr = (r & 3) + 8 * (r >> 2) + 4 * hi;
      const float li = __shfl(linv, qr);
      op[(size_t)(q0 + qr) * HD + l31]      = o0[r] * li;
      op[(size_t)(q0 + qr) * HD + 32 + l31] = o1[r] * li;
    }
  }
}

extern "C" void kernel_launch(void* const* d_in, const int* in_sizes, int n_in,
                              void* d_out, int out_size, void* d_ws, size_t ws_size,
                              hipStream_t stream) {
  const float* x = (const float*)d_in[0];
  const float* W = (const float*)d_in[1];
  float* out = (float*)d_out;

  char* ws = (char*)d_ws;
  bf16_t* xb  = (bf16_t*)(ws);
  bf16_t* wb  = (bf16_t*)(ws + 16777216);
  bf16_t* Qb  = (bf16_t*)(ws + 16777216 + 6291456);
  bf16_t* Kb  = Qb + 8388608;
  bf16_t* Vtb = Kb + 8388608;

  cvt_f32_bf16<<<2048, 256, 0, stream>>>(x, xb, (M_TOT * D_MODEL) / 4);
  cvt_f32_bf16<<<1024, 256, 0, stream>>>(W, wb, (N_TOT * D_MODEL) / 4);

  dim3 ggrid(N_TOT / 128, M_TOT / 128);   // (24, 64)
  qkv_gemm<<<ggrid, 256, 0, stream>>>(xb, wb, Qb, Kb, Vtb);

  dim3 agrid(8, B_SZ * N_HEAD);  // 512 blocks; every wave = exactly 65 tiles
  attn_fwd<<<agrid, 256, 0, stream>>>(Qb, Kb, Vtb, out);
}

// Round 8
// 241.717 us; speedup vs baseline: 2.3479x; 1.0024x over previous
//
#include <hip/hip_runtime.h>
#include <hip/hip_bf16.h>
#include <math.h>

#define D_MODEL 1024
#define N_HEAD  16
#define HD      64
#define B_SZ    4
#define T_SEQ   2048
#define M_TOT   (B_SZ * T_SEQ)   // 8192
#define N_TOT   (3 * D_MODEL)    // 3072

typedef __bf16 bf16_t;
typedef __bf16 bf16x8 __attribute__((ext_vector_type(8)));
typedef __bf16 bf16x4 __attribute__((ext_vector_type(4)));
typedef __bf16 bf16x2 __attribute__((ext_vector_type(2)));
typedef float  f32x4  __attribute__((ext_vector_type(4)));
typedef float  f32x16 __attribute__((ext_vector_type(16)));
typedef int    i32x4  __attribute__((ext_vector_type(4)));

// softmax scale folded with log2(e): scores end up in log2 domain -> exp2f
#define Q_PRESCALE 0.18033688011112042f   // (1/8) * log2(e)

// ---------------- fp32 -> bf16 conversion (vectorized) ----------------
__global__ __launch_bounds__(256) void cvt_f32_bf16(const float* __restrict__ in,
                                                    bf16_t* __restrict__ out, int n4) {
  int i = blockIdx.x * blockDim.x + threadIdx.x;
  int stride = gridDim.x * blockDim.x;
  for (; i < n4; i += stride) {
    float4 v = ((const float4*)in)[i];
    bf16x4 o;
    o[0] = (bf16_t)v.x; o[1] = (bf16_t)v.y; o[2] = (bf16_t)v.z; o[3] = (bf16_t)v.w;
    ((bf16x4*)out)[i] = o;
  }
}

// ---------------- QKV projection GEMM (bf16 MFMA, 128x128 tile) ----------------
__global__ __launch_bounds__(256) void qkv_gemm(const bf16_t* __restrict__ xb,
                                                const bf16_t* __restrict__ wb,
                                                bf16_t* __restrict__ Q,
                                                bf16_t* __restrict__ K,
                                                bf16_t* __restrict__ Vt) {
  __shared__ alignas(16) bf16_t a_lds[128 * 32];
  __shared__ alignas(16) bf16_t b_lds[128 * 32];
  const int tid  = threadIdx.x;
  const int wave = tid >> 6;
  const int lane = tid & 63;
  const int bm = blockIdx.y * 128;
  const int bn = blockIdx.x * 128;

  f32x4 acc[4][4] = {};

  const int aRow = lane >> 2;
  const int aK8  = (lane & 3) * 8;
  const int fr   = lane & 15;
  const int fk   = (lane >> 4) * 8;
  const int wm   = (wave >> 1) * 64;
  const int wn   = (wave & 1) * 64;

  for (int kk = 0; kk < D_MODEL; kk += 32) {
#pragma unroll
    for (int c = 0; c < 2; ++c) {
      const int chunk = wave * 2 + c;
      const bf16_t* gA = &xb[(size_t)(bm + chunk * 16 + aRow) * D_MODEL + kk + aK8];
      __builtin_amdgcn_global_load_lds(
          (__attribute__((address_space(1))) void*)(void*)gA,
          (__attribute__((address_space(3))) void*)&a_lds[chunk * 512], 16, 0, 0);
      const bf16_t* gB = &wb[(size_t)(bn + chunk * 16 + aRow) * D_MODEL + kk + aK8];
      __builtin_amdgcn_global_load_lds(
          (__attribute__((address_space(1))) void*)(void*)gB,
          (__attribute__((address_space(3))) void*)&b_lds[chunk * 512], 16, 0, 0);
    }
    __syncthreads();

    bf16x8 af[4], bfr[4];
#pragma unroll
    for (int mt = 0; mt < 4; ++mt)
      af[mt] = *(const bf16x8*)&a_lds[(wm + mt * 16 + fr) * 32 + fk];
#pragma unroll
    for (int nt = 0; nt < 4; ++nt)
      bfr[nt] = *(const bf16x8*)&b_lds[(wn + nt * 16 + fr) * 32 + fk];
#pragma unroll
    for (int mt = 0; mt < 4; ++mt)
#pragma unroll
      for (int nt = 0; nt < 4; ++nt)
        acc[mt][nt] = __builtin_amdgcn_mfma_f32_16x16x32_bf16(af[mt], bfr[nt], acc[mt][nt], 0, 0, 0);
    __syncthreads();
  }

  const int cRowBase = (lane >> 4) * 4;
  const int cCol     = lane & 15;
#pragma unroll
  for (int mt = 0; mt < 4; ++mt) {
#pragma unroll
    for (int nt = 0; nt < 4; ++nt) {
      const int n   = bn + wn + nt * 16 + cCol;
      const int sec = n >> 10;            // 0=Q 1=K 2=V
      const int hn  = n & 1023;
      const int h   = hn >> 6;
      const int d   = hn & 63;
#pragma unroll
      for (int r = 0; r < 4; ++r) {
        const int m = bm + wm + mt * 16 + cRowBase + r;
        const int b = m >> 11;
        const int t = m & 2047;
        const float v = acc[mt][nt][r];
        if (sec == 0) {
          Q[((size_t)(b * N_HEAD + h) * T_SEQ + t) * HD + d] = (bf16_t)(v * Q_PRESCALE);
        } else if (sec == 1) {
          K[((size_t)(b * N_HEAD + h) * T_SEQ + t) * HD + d] = (bf16_t)v;
        } else {
          Vt[((size_t)(b * N_HEAD + h) * HD + d) * T_SEQ + t] = (bf16_t)v;
        }
      }
    }
  }
}

// ---------------- helpers ----------------
__device__ inline int pack_bf16(float lo, float hi) {
  bf16x2 v; v[0] = (bf16_t)lo; v[1] = (bf16_t)hi;
  return __builtin_bit_cast(int, v);
}
// P-redistribution swap: ROUND-2-PROVEN inline asm. Only ever called with
// provably-distinct SSA values (different p[] packs), so no coalescing hazard.
__device__ inline void permswap(int& a, int& b) {
  asm volatile("v_permlane32_swap_b32 %0, %1" : "+v"(a), "+v"(b));
}

__device__ inline void loadK4(bf16x8 k[4], const bf16_t* __restrict__ Kp,
                              int kv0, int l31, int hi) {
#pragma unroll
  for (int c = 0; c < 4; ++c)
    k[c] = *(const bf16x8*)&Kp[(size_t)(kv0 + l31) * HD + c * 16 + hi * 8];
}
__device__ inline void loadV4(bf16x8 v[4], const bf16_t* __restrict__ Vp,
                              int kv0, int l31, int hi) {
  v[0] = *(const bf16x8*)&Vp[(size_t)(l31) * T_SEQ + kv0 + hi * 8];
  v[1] = *(const bf16x8*)&Vp[(size_t)(l31) * T_SEQ + kv0 + 16 + hi * 8];
  v[2] = *(const bf16x8*)&Vp[(size_t)(32 + l31) * T_SEQ + kv0 + hi * 8];
  v[3] = *(const bf16x8*)&Vp[(size_t)(32 + l31) * T_SEQ + kv0 + 16 + hi * 8];
}

// ---------------- causal flash attention, swapped 32x32 MFMA, no LDS ----------------
// Q [BH,T,64] prescaled by (1/8)*log2e, K [BH,T,64], Vt [BH,64,T], out fp32 [BH,T,64]
//
// Work distribution: each wave processes TWO complementary chunks c and 63-c:
// 65 tiles for EVERY wave (uniform, placement-independent).
// XCD-locality (round-7 lesson): flat block id f -> XCD f&7 (round-robin
// heuristic). Decode bh = 8*(f&7) + ((f>>3)&7) so ALL 8 blocks of one bh share
// an XCD; each XCD serves 8 heads = 4 MB K/V ~= its L2 -> K/V loads become L2
// hits instead of the measured 5x HBM re-fetch (155 MB vs 32 MB of KV data).
__global__ __launch_bounds__(256) void attn_fwd(const bf16_t* __restrict__ Q,
                                                const bf16_t* __restrict__ K,
                                                const bf16_t* __restrict__ Vt,
                                                float* __restrict__ out) {
  const int tid  = threadIdx.x;
  const int wave = tid >> 6;
  const int lane = tid & 63;
  const int l31  = lane & 31;
  const int hi   = lane >> 5;

  const int f    = blockIdx.x;          // 0..511
  const int bh   = ((f & 7) << 3) | ((f >> 3) & 7);
  const int bx   = f >> 6;              // 0..7
  const int c_lo = bx * 4 + wave;       // 0..31

  const bf16_t* Qp = Q  + (size_t)bh * T_SEQ * HD;
  const bf16_t* Kp = K  + (size_t)bh * T_SEQ * HD;
  const bf16_t* Vp = Vt + (size_t)bh * HD * T_SEQ;
  float* op = out + (size_t)bh * T_SEQ * HD;

  for (int half = 0; half < 2; ++half) {
    const int chunk = half ? (63 - c_lo) : c_lo;
    const int q0 = chunk * 32;

    // Q fragments (B-operand: col=lane&31, k=(lane>>5)*8+i)
    bf16x8 qf[4];
#pragma unroll
    for (int c = 0; c < 4; ++c)
      qf[c] = *(const bf16x8*)&Qp[(size_t)(q0 + l31) * HD + c * 16 + hi * 8];

    f32x16 o0 = {}, o1 = {};
    float m_run = -INFINITY;
    float l_run = 0.f;          // per-lane HALF-row partial sum

    bf16x8 kA[4], vA[4];
    loadK4(kA, Kp, 0, l31, hi);

    for (int kv0 = 0; kv0 <= q0; kv0 += 32) {
      // V for THIS tile: issue now, consumed after softmax
      loadV4(vA, Vp, kv0, l31, hi);

      // S^T = K_tile x Q_tile^T : D[key][q], key = koff(r)+kv0, q = l31+q0
      f32x16 st = {};
      __builtin_amdgcn_s_setprio(1);
#pragma unroll
      for (int c = 0; c < 4; ++c)
        st = __builtin_amdgcn_mfma_f32_32x32x16_bf16(kA[c], qf[c], st, 0, 0, 0);
      __builtin_amdgcn_s_setprio(0);

      // prefetch K for NEXT tile (regalloc double-buffers; hides under softmax+PV)
      const int nxt = (kv0 + 32 <= q0) ? kv0 + 32 : kv0;
      loadK4(kA, Kp, nxt, l31, hi);

      if (kv0 == q0) {   // only the diagonal tile needs causal masking
#pragma unroll
        for (int r = 0; r < 16; ++r) {
          const int koff = (r & 3) + 8 * (r >> 2) + 4 * hi;
          st[r] = (koff > l31) ? -INFINITY : st[r];
        }
      }
      // per-lane local max over this lane's 16 scores (VALU tree, no cross-lane)
      float pm = fmaxf(fmaxf(fmaxf(st[0], st[1]), fmaxf(st[2], st[3])),
                       fmaxf(fmaxf(st[4], st[5]), fmaxf(st[6], st[7])));
      pm = fmaxf(pm, fmaxf(fmaxf(fmaxf(st[8], st[9]), fmaxf(st[10], st[11])),
                           fmaxf(fmaxf(st[12], st[13]), fmaxf(st[14], st[15]))));

      // defer-max (T13): rescale only when the local max grows past m_run+8.
      // Cross-half max exchange lives ONLY here (first tile always triggers,
      // establishing row-consistent m_run across the two half-lanes).
      if (__any(!(pm <= m_run + 8.f))) {
        const float pm_full = fmaxf(pm, __shfl_xor(pm, 32));
        const float m_new = fmaxf(m_run, pm_full);
        const float alpha = exp2f(m_run - m_new);   // first tile: exp2(-inf)=0
        m_run = m_new;
        l_run *= alpha;
#pragma unroll
        for (int r = 0; r < 16; ++r) {
          const int qr = (r & 3) + 8 * (r >> 2) + 4 * hi;
          const float av = __shfl(alpha, qr);
          o0[r] *= av; o1[r] *= av;
        }
      }

      float p[16];
#pragma unroll
      for (int r = 0; r < 16; ++r) p[r] = exp2f(st[r] - m_run);
      float s0 = (p[0] + p[1]) + (p[2] + p[3]);
      float s1 = (p[4] + p[5]) + (p[6] + p[7]);
      float s2 = (p[8] + p[9]) + (p[10] + p[11]);
      float s3 = (p[12] + p[13]) + (p[14] + p[15]);
      l_run += (s0 + s1) + (s2 + s3);   // per-lane partial; halves combined at end

      // pack P to bf16 pairs; permlane32_swap redistributes into PV A-fragments
      int a01 = pack_bf16(p[0],  p[1]),  a23 = pack_bf16(p[2],  p[3]);
      int b01 = pack_bf16(p[4],  p[5]),  b23 = pack_bf16(p[6],  p[7]);
      int c01 = pack_bf16(p[8],  p[9]),  c23 = pack_bf16(p[10], p[11]);
      int d01 = pack_bf16(p[12], p[13]), d23 = pack_bf16(p[14], p[15]);
      permswap(a01, b01); permswap(a23, b23);
      permswap(c01, d01); permswap(c23, d23);
      i32x4 w1 = {a01, a23, b01, b23};   // keys kv0+0..15
      i32x4 w2 = {c01, c23, d01, d23};   // keys kv0+16..31
      bf16x8 f1 = __builtin_bit_cast(bf16x8, w1);
      bf16x8 f2 = __builtin_bit_cast(bf16x8, w2);

      // O += P @ V  (V^T rows contiguous in key)
      __builtin_amdgcn_s_setprio(1);
      o0 = __builtin_amdgcn_mfma_f32_32x32x16_bf16(f1, vA[0], o0, 0, 0, 0);
      o0 = __builtin_amdgcn_mfma_f32_32x32x16_bf16(f2, vA[1], o0, 0, 0, 0);
      o1 = __builtin_amdgcn_mfma_f32_32x32x16_bf16(f1, vA[2], o1, 0, 0, 0);
      o1 = __builtin_amdgcn_mfma_f32_32x32x16_bf16(f2, vA[3], o1, 0, 0, 0);
      __builtin_amdgcn_s_setprio(0);
    }

    // epilogue: combine l halves, out = O / l
    const float l_tot = l_run + __shfl_xor(l_run, 32);
    const float linv = 1.f / l_tot;
#pragma unroll
    for (int r = 0; r < 16; ++r) {
      const int qr = (r & 3) + 8 * (r >> 2) + 4 * hi;
      const float li = __shfl(linv, qr);
      op[(size_t)(q0 + qr) * HD + l31]      = o0[r] * li;
      op[(size_t)(q0 + qr) * HD + 32 + l31] = o1[r] * li;
    }
  }
}

extern "C" void kernel_launch(void* const* d_in, const int* in_sizes, int n_in,
                              void* d_out, int out_size, void* d_ws, size_t ws_size,
                              hipStream_t stream) {
  const float* x = (const float*)d_in[0];
  const float* W = (const float*)d_in[1];
  float* out = (float*)d_out;

  char* ws = (char*)d_ws;
  bf16_t* xb  = (bf16_t*)(ws);
  bf16_t* wb  = (bf16_t*)(ws + 16777216);
  bf16_t* Qb  = (bf16_t*)(ws + 16777216 + 6291456);
  bf16_t* Kb  = Qb + 8388608;
  bf16_t* Vtb = Kb + 8388608;

  cvt_f32_bf16<<<2048, 256, 0, stream>>>(x, xb, (M_TOT * D_MODEL) / 4);
  cvt_f32_bf16<<<1024, 256, 0, stream>>>(W, wb, (N_TOT * D_MODEL) / 4);

  dim3 ggrid(N_TOT / 128, M_TOT / 128);   // (24, 64)
  qkv_gemm<<<ggrid, 256, 0, stream>>>(xb, wb, Qb, Kb, Vtb);

  // 512 blocks, 1-D: f&7 selects XCD (heuristic); all 8 blocks of a bh co-locate
  attn_fwd<<<512, 256, 0, stream>>>(Qb, Kb, Vtb, out);
}

// Round 9
// 176.895 us; speedup vs baseline: 3.2083x; 1.3664x over previous
//
#include <hip/hip_runtime.h>
#include <hip/hip_bf16.h>
#include <math.h>

#define D_MODEL 1024
#define N_HEAD  16
#define HD      64
#define B_SZ    4
#define T_SEQ   2048
#define M_TOT   (B_SZ * T_SEQ)   // 8192
#define N_TOT   (3 * D_MODEL)    // 3072

typedef __bf16 bf16_t;
typedef __bf16 bf16x8 __attribute__((ext_vector_type(8)));
typedef __bf16 bf16x4 __attribute__((ext_vector_type(4)));
typedef __bf16 bf16x2 __attribute__((ext_vector_type(2)));
typedef float  f32x4  __attribute__((ext_vector_type(4)));
typedef float  f32x16 __attribute__((ext_vector_type(16)));
typedef int    i32x4  __attribute__((ext_vector_type(4)));

// softmax scale folded with log2(e): scores end up in log2 domain -> exp2f
#define Q_PRESCALE 0.18033688011112042f   // (1/8) * log2(e)

// ---------------- fp32 -> bf16 conversion (vectorized) ----------------
__global__ __launch_bounds__(256) void cvt_f32_bf16(const float* __restrict__ in,
                                                    bf16_t* __restrict__ out, int n4) {
  int i = blockIdx.x * blockDim.x + threadIdx.x;
  int stride = gridDim.x * blockDim.x;
  for (; i < n4; i += stride) {
    float4 v = ((const float4*)in)[i];
    bf16x4 o;
    o[0] = (bf16_t)v.x; o[1] = (bf16_t)v.y; o[2] = (bf16_t)v.z; o[3] = (bf16_t)v.w;
    ((bf16x4*)out)[i] = o;
  }
}

// ---------------- QKV projection GEMM (bf16 MFMA, 128x128 tile) ----------------
// K and V are written in FRAGMENT-TILED layouts so the attention kernel's loads
// are lane-linear (round-8 lesson: row-strided K/V made every attn load a
// 32-cache-line gather -> ~256 line-requests/tile -> TA serialization, the
// real 5000-cyc/tile limiter; FETCH_SIZE was already fine).
//  Kf[bh][t>>5][d>>4][(d>>3)&1][t&31][d&7]           (tile: 4x512 bf16)
//  Vf[bh][t>>5][(d>>5)*2+((t&31)>>4)][((t&31)>>3)&1][d&31][t&7]
__global__ __launch_bounds__(256) void qkv_gemm(const bf16_t* __restrict__ xb,
                                                const bf16_t* __restrict__ wb,
                                                bf16_t* __restrict__ Q,
                                                bf16_t* __restrict__ Kf,
                                                bf16_t* __restrict__ Vf) {
  __shared__ alignas(16) bf16_t a_lds[128 * 32];
  __shared__ alignas(16) bf16_t b_lds[128 * 32];
  const int tid  = threadIdx.x;
  const int wave = tid >> 6;
  const int lane = tid & 63;
  const int bm = blockIdx.y * 128;
  const int bn = blockIdx.x * 128;

  f32x4 acc[4][4] = {};

  const int aRow = lane >> 2;
  const int aK8  = (lane & 3) * 8;
  const int fr   = lane & 15;
  const int fk   = (lane >> 4) * 8;
  const int wm   = (wave >> 1) * 64;
  const int wn   = (wave & 1) * 64;

  for (int kk = 0; kk < D_MODEL; kk += 32) {
#pragma unroll
    for (int c = 0; c < 2; ++c) {
      const int chunk = wave * 2 + c;
      const bf16_t* gA = &xb[(size_t)(bm + chunk * 16 + aRow) * D_MODEL + kk + aK8];
      __builtin_amdgcn_global_load_lds(
          (__attribute__((address_space(1))) void*)(void*)gA,
          (__attribute__((address_space(3))) void*)&a_lds[chunk * 512], 16, 0, 0);
      const bf16_t* gB = &wb[(size_t)(bn + chunk * 16 + aRow) * D_MODEL + kk + aK8];
      __builtin_amdgcn_global_load_lds(
          (__attribute__((address_space(1))) void*)(void*)gB,
          (__attribute__((address_space(3))) void*)&b_lds[chunk * 512], 16, 0, 0);
    }
    __syncthreads();

    bf16x8 af[4], bfr[4];
#pragma unroll
    for (int mt = 0; mt < 4; ++mt)
      af[mt] = *(const bf16x8*)&a_lds[(wm + mt * 16 + fr) * 32 + fk];
#pragma unroll
    for (int nt = 0; nt < 4; ++nt)
      bfr[nt] = *(const bf16x8*)&b_lds[(wn + nt * 16 + fr) * 32 + fk];
#pragma unroll
    for (int mt = 0; mt < 4; ++mt)
#pragma unroll
      for (int nt = 0; nt < 4; ++nt)
        acc[mt][nt] = __builtin_amdgcn_mfma_f32_16x16x32_bf16(af[mt], bfr[nt], acc[mt][nt], 0, 0, 0);
    __syncthreads();
  }

  const int cRowBase = (lane >> 4) * 4;
  const int cCol     = lane & 15;
#pragma unroll
  for (int mt = 0; mt < 4; ++mt) {
#pragma unroll
    for (int nt = 0; nt < 4; ++nt) {
      const int n   = bn + wn + nt * 16 + cCol;
      const int sec = n >> 10;            // 0=Q 1=K 2=V
      const int hn  = n & 1023;
      const int h   = hn >> 6;
      const int d   = hn & 63;
#pragma unroll
      for (int r = 0; r < 4; ++r) {
        const int m = bm + wm + mt * 16 + cRowBase + r;
        const int b = m >> 11;
        const int t = m & 2047;
        const float v = acc[mt][nt][r];
        const size_t bhOff = (size_t)(b * N_HEAD + h) * (T_SEQ * HD);
        if (sec == 0) {
          Q[bhOff + (size_t)t * HD + d] = (bf16_t)(v * Q_PRESCALE);
        } else if (sec == 1) {
          const int kvt = t >> 5, lk = t & 31;
          const int cc = d >> 4, h2 = (d >> 3) & 1, j = d & 7;
          Kf[bhOff + (size_t)(((kvt * 4 + cc) * 64 + h2 * 32 + lk) * 8 + j)] = (bf16_t)v;
        } else {
          const int kvt = t >> 5, tt = t & 31;
          const int idx = (d >> 5) * 2 + (tt >> 4), h2 = (tt >> 3) & 1, j = tt & 7;
          Vf[bhOff + (size_t)(((kvt * 4 + idx) * 64 + h2 * 32 + (d & 31)) * 8 + j)] = (bf16_t)v;
        }
      }
    }
  }
}

// ---------------- helpers ----------------
__device__ inline int pack_bf16(float lo, float hi) {
  bf16x2 v; v[0] = (bf16_t)lo; v[1] = (bf16_t)hi;
  return __builtin_bit_cast(int, v);
}
// P-redistribution swap: ROUND-2-PROVEN inline asm. Only ever called with
// provably-distinct SSA values (different p[] packs), so no coalescing hazard.
__device__ inline void permswap(int& a, int& b) {
  asm volatile("v_permlane32_swap_b32 %0, %1" : "+v"(a), "+v"(b));
}

// Fragment-tiled loads: 4 consecutive lane-linear 16B loads (1 KB/instr).
__device__ inline void loadK4(bf16x8 k[4], const bf16_t* __restrict__ Kbase,
                              int kv0, int lane) {
  const bf16_t* p = Kbase + (size_t)(kv0 >> 5) * 2048 + lane * 8;
#pragma unroll
  for (int c = 0; c < 4; ++c) k[c] = *(const bf16x8*)(p + c * 512);
}
__device__ inline void loadV4(bf16x8 v[4], const bf16_t* __restrict__ Vbase,
                              int kv0, int lane) {
  const bf16_t* p = Vbase + (size_t)(kv0 >> 5) * 2048 + lane * 8;
#pragma unroll
  for (int idx = 0; idx < 4; ++idx) v[idx] = *(const bf16x8*)(p + idx * 512);
}

// ---------------- causal flash attention, swapped 32x32 MFMA, no LDS ----------------
// Q [BH,T,64] prescaled by (1/8)*log2e; Kf/Vf fragment-tiled; out fp32 [BH,T,64]
// Each wave: two complementary chunks c and 63-c = 65 tiles (uniform).
// XCD-locality: all 8 blocks of one bh share f&7 -> same XCD L2.
__global__ __launch_bounds__(256) void attn_fwd(const bf16_t* __restrict__ Q,
                                                const bf16_t* __restrict__ Kf,
                                                const bf16_t* __restrict__ Vf,
                                                float* __restrict__ out) {
  const int tid  = threadIdx.x;
  const int wave = tid >> 6;
  const int lane = tid & 63;
  const int l31  = lane & 31;
  const int hi   = lane >> 5;

  const int f    = blockIdx.x;          // 0..511
  const int bh   = ((f & 7) << 3) | ((f >> 3) & 7);
  const int bx   = f >> 6;              // 0..7
  const int c_lo = bx * 4 + wave;       // 0..31

  const bf16_t* Qp = Q  + (size_t)bh * T_SEQ * HD;
  const bf16_t* Kp = Kf + (size_t)bh * T_SEQ * HD;
  const bf16_t* Vp = Vf + (size_t)bh * T_SEQ * HD;
  float* op = out + (size_t)bh * T_SEQ * HD;

  for (int half = 0; half < 2; ++half) {
    const int chunk = half ? (63 - c_lo) : c_lo;
    const int q0 = chunk * 32;

    // Q fragments (B-operand: col=lane&31, k=(lane>>5)*8+i)
    bf16x8 qf[4];
#pragma unroll
    for (int c = 0; c < 4; ++c)
      qf[c] = *(const bf16x8*)&Qp[(size_t)(q0 + l31) * HD + c * 16 + hi * 8];

    f32x16 o0 = {}, o1 = {};
    float m_run = -INFINITY;
    float l_run = 0.f;          // per-lane HALF-row partial sum

    bf16x8 kA[4], vA[4];
    loadK4(kA, Kp, 0, lane);

    for (int kv0 = 0; kv0 <= q0; kv0 += 32) {
      // V for THIS tile: issue now, consumed after softmax
      loadV4(vA, Vp, kv0, lane);

      // S^T = K_tile x Q_tile^T : D[key][q], key = koff(r)+kv0, q = l31+q0
      f32x16 st = {};
      __builtin_amdgcn_s_setprio(1);
#pragma unroll
      for (int c = 0; c < 4; ++c)
        st = __builtin_amdgcn_mfma_f32_32x32x16_bf16(kA[c], qf[c], st, 0, 0, 0);
      __builtin_amdgcn_s_setprio(0);

      // prefetch K for NEXT tile (regalloc double-buffers; hides under softmax+PV)
      const int nxt = (kv0 + 32 <= q0) ? kv0 + 32 : kv0;
      loadK4(kA, Kp, nxt, lane);

      if (kv0 == q0) {   // only the diagonal tile needs causal masking
#pragma unroll
        for (int r = 0; r < 16; ++r) {
          const int koff = (r & 3) + 8 * (r >> 2) + 4 * hi;
          st[r] = (koff > l31) ? -INFINITY : st[r];
        }
      }
      // per-lane local max over this lane's 16 scores (VALU tree, no cross-lane)
      float pm = fmaxf(fmaxf(fmaxf(st[0], st[1]), fmaxf(st[2], st[3])),
                       fmaxf(fmaxf(st[4], st[5]), fmaxf(st[6], st[7])));
      pm = fmaxf(pm, fmaxf(fmaxf(fmaxf(st[8], st[9]), fmaxf(st[10], st[11])),
                           fmaxf(fmaxf(st[12], st[13]), fmaxf(st[14], st[15]))));

      // defer-max (T13): rescale only when the local max grows past m_run+8.
      // Cross-half max exchange lives ONLY here (first tile always triggers,
      // establishing row-consistent m_run across the two half-lanes).
      if (__any(!(pm <= m_run + 8.f))) {
        const float pm_full = fmaxf(pm, __shfl_xor(pm, 32));
        const float m_new = fmaxf(m_run, pm_full);
        const float alpha = exp2f(m_run - m_new);   // first tile: exp2(-inf)=0
        m_run = m_new;
        l_run *= alpha;
#pragma unroll
        for (int r = 0; r < 16; ++r) {
          const int qr = (r & 3) + 8 * (r >> 2) + 4 * hi;
          const float av = __shfl(alpha, qr);
          o0[r] *= av; o1[r] *= av;
        }
      }

      float p[16];
#pragma unroll
      for (int r = 0; r < 16; ++r) p[r] = exp2f(st[r] - m_run);
      float s0 = (p[0] + p[1]) + (p[2] + p[3]);
      float s1 = (p[4] + p[5]) + (p[6] + p[7]);
      float s2 = (p[8] + p[9]) + (p[10] + p[11]);
      float s3 = (p[12] + p[13]) + (p[14] + p[15]);
      l_run += (s0 + s1) + (s2 + s3);   // per-lane partial; halves combined at end

      // pack P to bf16 pairs; permlane32_swap redistributes into PV A-fragments
      int a01 = pack_bf16(p[0],  p[1]),  a23 = pack_bf16(p[2],  p[3]);
      int b01 = pack_bf16(p[4],  p[5]),  b23 = pack_bf16(p[6],  p[7]);
      int c01 = pack_bf16(p[8],  p[9]),  c23 = pack_bf16(p[10], p[11]);
      int d01 = pack_bf16(p[12], p[13]), d23 = pack_bf16(p[14], p[15]);
      permswap(a01, b01); permswap(a23, b23);
      permswap(c01, d01); permswap(c23, d23);
      i32x4 w1 = {a01, a23, b01, b23};   // keys kv0+0..15
      i32x4 w2 = {c01, c23, d01, d23};   // keys kv0+16..31
      bf16x8 f1 = __builtin_bit_cast(bf16x8, w1);
      bf16x8 f2 = __builtin_bit_cast(bf16x8, w2);

      // O += P @ V  (Vf rows contiguous in key)
      __builtin_amdgcn_s_setprio(1);
      o0 = __builtin_amdgcn_mfma_f32_32x32x16_bf16(f1, vA[0], o0, 0, 0, 0);
      o0 = __builtin_amdgcn_mfma_f32_32x32x16_bf16(f2, vA[1], o0, 0, 0, 0);
      o1 = __builtin_amdgcn_mfma_f32_32x32x16_bf16(f1, vA[2], o1, 0, 0, 0);
      o1 = __builtin_amdgcn_mfma_f32_32x32x16_bf16(f2, vA[3], o1, 0, 0, 0);
      __builtin_amdgcn_s_setprio(0);
    }

    // epilogue: combine l halves, out = O / l
    const float l_tot = l_run + __shfl_xor(l_run, 32);
    const float linv = 1.f / l_tot;
#pragma unroll
    for (int r = 0; r < 16; ++r) {
      const int qr = (r & 3) + 8 * (r >> 2) + 4 * hi;
      const float li = __shfl(linv, qr);
      op[(size_t)(q0 + qr) * HD + l31]      = o0[r] * li;
      op[(size_t)(q0 + qr) * HD + 32 + l31] = o1[r] * li;
    }
  }
}

extern "C" void kernel_launch(void* const* d_in, const int* in_sizes, int n_in,
                              void* d_out, int out_size, void* d_ws, size_t ws_size,
                              hipStream_t stream) {
  const float* x = (const float*)d_in[0];
  const float* W = (const float*)d_in[1];
  float* out = (float*)d_out;

  char* ws = (char*)d_ws;
  bf16_t* xb  = (bf16_t*)(ws);
  bf16_t* wb  = (bf16_t*)(ws + 16777216);
  bf16_t* Qb  = (bf16_t*)(ws + 16777216 + 6291456);
  bf16_t* Kfb = Qb + 8388608;
  bf16_t* Vfb = Kfb + 8388608;

  cvt_f32_bf16<<<2048, 256, 0, stream>>>(x, xb, (M_TOT * D_MODEL) / 4);
  cvt_f32_bf16<<<1024, 256, 0, stream>>>(W, wb, (N_TOT * D_MODEL) / 4);

  dim3 ggrid(N_TOT / 128, M_TOT / 128);   // (24, 64)
  qkv_gemm<<<ggrid, 256, 0, stream>>>(xb, wb, Qb, Kfb, Vfb);

  // 512 blocks, 1-D: f&7 selects XCD (heuristic); all 8 blocks of a bh co-locate
  attn_fwd<<<512, 256, 0, stream>>>(Qb, Kfb, Vfb, out);
}

// Round 10
// 165.617 us; speedup vs baseline: 3.4267x; 1.0681x over previous
//
#include <hip/hip_runtime.h>
#include <hip/hip_bf16.h>
#include <math.h>

#define D_MODEL 1024
#define N_HEAD  16
#define HD      64
#define B_SZ    4
#define T_SEQ   2048
#define M_TOT   (B_SZ * T_SEQ)   // 8192
#define N_TOT   (3 * D_MODEL)    // 3072

typedef __bf16 bf16_t;
typedef __bf16 bf16x8 __attribute__((ext_vector_type(8)));
typedef __bf16 bf16x4 __attribute__((ext_vector_type(4)));
typedef __bf16 bf16x2 __attribute__((ext_vector_type(2)));
typedef float  f32x4  __attribute__((ext_vector_type(4)));
typedef float  f32x16 __attribute__((ext_vector_type(16)));
typedef int    i32x4  __attribute__((ext_vector_type(4)));

// softmax scale folded with log2(e): scores end up in log2 domain -> exp2f
#define Q_PRESCALE 0.18033688011112042f   // (1/8) * log2(e)

// ---------------- fp32 -> bf16 conversion (vectorized) ----------------
__global__ __launch_bounds__(256) void cvt_f32_bf16(const float* __restrict__ in,
                                                    bf16_t* __restrict__ out, int n4) {
  int i = blockIdx.x * blockDim.x + threadIdx.x;
  int stride = gridDim.x * blockDim.x;
  for (; i < n4; i += stride) {
    float4 v = ((const float4*)in)[i];
    bf16x4 o;
    o[0] = (bf16_t)v.x; o[1] = (bf16_t)v.y; o[2] = (bf16_t)v.z; o[3] = (bf16_t)v.w;
    ((bf16x4*)out)[i] = o;
  }
}

// ---------------- QKV projection GEMM (bf16 MFMA, 128x128 tile) ----------------
// Round-10 changes (GEMM was 119 us, MfmaUtil 18%, 6.3M bank conflicts):
//  (a) double-buffered LDS, stage(t+1) issued BEFORE compute(t) -> staging
//      latency hides under ds_read+MFMA (T3 minimum-2-phase, m230 pattern);
//  (b) LDS XOR-swizzle col8 ^= (row>>1)&3 via PRE-SWIZZLED GLOBAL SOURCE
//      (linear LDS dest, rule #21) + same XOR on read -> 8-way bank conflict
//      becomes 2-way (free). Swizzle permutes cols within one row's 64 B
//      segment -> global coalescing unchanged.
// K and V outputs are FRAGMENT-TILED for the attention kernel (round-9 win):
//  Kf[bh][t>>5][d>>4][(d>>3)&1][t&31][d&7]
//  Vf[bh][t>>5][(d>>5)*2+((t&31)>>4)][((t&31)>>3)&1][d&31][t&7]
__global__ __launch_bounds__(256) void qkv_gemm(const bf16_t* __restrict__ xb,
                                                const bf16_t* __restrict__ wb,
                                                bf16_t* __restrict__ Q,
                                                bf16_t* __restrict__ Kf,
                                                bf16_t* __restrict__ Vf) {
  __shared__ alignas(16) bf16_t a_lds[2][128 * 32];
  __shared__ alignas(16) bf16_t b_lds[2][128 * 32];
  const int tid  = threadIdx.x;
  const int wave = tid >> 6;
  const int lane = tid & 63;
  const int bm = blockIdx.y * 128;
  const int bn = blockIdx.x * 128;

  f32x4 acc[4][4] = {};

  const int sRow  = lane >> 2;                        // row within 16-row chunk
  const int sCol8 = (lane & 3) ^ ((lane >> 3) & 3);   // pre-swizzled global col8
  const int fr = lane & 15;
  const int fk = lane >> 4;                           // fragment k-group 0..3
  const int wm = (wave >> 1) * 64;
  const int wn = (wave & 1) * 64;

  auto stage = [&](int buf, int kk) {
#pragma unroll
    for (int c = 0; c < 2; ++c) {
      const int chunk = wave * 2 + c;
      const bf16_t* gA = &xb[(size_t)(bm + chunk * 16 + sRow) * D_MODEL + kk + sCol8 * 8];
      __builtin_amdgcn_global_load_lds(
          (__attribute__((address_space(1))) void*)(void*)gA,
          (__attribute__((address_space(3))) void*)&a_lds[buf][chunk * 512], 16, 0, 0);
      const bf16_t* gB = &wb[(size_t)(bn + chunk * 16 + sRow) * D_MODEL + kk + sCol8 * 8];
      __builtin_amdgcn_global_load_lds(
          (__attribute__((address_space(1))) void*)(void*)gB,
          (__attribute__((address_space(3))) void*)&b_lds[buf][chunk * 512], 16, 0, 0);
    }
  };

  auto compute = [&](int buf) {
    bf16x8 af[4], bfr[4];
#pragma unroll
    for (int mt = 0; mt < 4; ++mt) {
      const int row = wm + mt * 16 + fr;
      af[mt] = *(const bf16x8*)&a_lds[buf][row * 32 + (fk ^ ((fr >> 1) & 3)) * 8];
    }
#pragma unroll
    for (int nt = 0; nt < 4; ++nt) {
      const int row = wn + nt * 16 + fr;
      bfr[nt] = *(const bf16x8*)&b_lds[buf][row * 32 + (fk ^ ((fr >> 1) & 3)) * 8];
    }
    __builtin_amdgcn_s_setprio(1);
#pragma unroll
    for (int mt = 0; mt < 4; ++mt)
#pragma unroll
      for (int nt = 0; nt < 4; ++nt)
        acc[mt][nt] = __builtin_amdgcn_mfma_f32_16x16x32_bf16(af[mt], bfr[nt], acc[mt][nt], 0, 0, 0);
    __builtin_amdgcn_s_setprio(0);
  };

  stage(0, 0);
  __syncthreads();                 // drains vmcnt: buf0 ready
  int cur = 0;
  for (int t = 0; t < (D_MODEL / 32) - 1; ++t) {
    stage(cur ^ 1, (t + 1) * 32);  // issue next-tile loads FIRST (latency hides below)
    compute(cur);
    __syncthreads();               // drains vmcnt(0)+lgkmcnt(0): next buf ready, reads done
    cur ^= 1;
  }
  compute(cur);                    // last tile, no prefetch

  // epilogue: scatter into Q (scaled), fragment-tiled Kf, Vf
  const int cRowBase = (lane >> 4) * 4;
  const int cCol     = lane & 15;
#pragma unroll
  for (int mt = 0; mt < 4; ++mt) {
#pragma unroll
    for (int nt = 0; nt < 4; ++nt) {
      const int n   = bn + wn + nt * 16 + cCol;
      const int sec = n >> 10;            // 0=Q 1=K 2=V
      const int hn  = n & 1023;
      const int h   = hn >> 6;
      const int d   = hn & 63;
#pragma unroll
      for (int r = 0; r < 4; ++r) {
        const int m = bm + wm + mt * 16 + cRowBase + r;
        const int b = m >> 11;
        const int t = m & 2047;
        const float v = acc[mt][nt][r];
        const size_t bhOff = (size_t)(b * N_HEAD + h) * (T_SEQ * HD);
        if (sec == 0) {
          Q[bhOff + (size_t)t * HD + d] = (bf16_t)(v * Q_PRESCALE);
        } else if (sec == 1) {
          const int kvt = t >> 5, lk = t & 31;
          const int cc = d >> 4, h2 = (d >> 3) & 1, j = d & 7;
          Kf[bhOff + (size_t)(((kvt * 4 + cc) * 64 + h2 * 32 + lk) * 8 + j)] = (bf16_t)v;
        } else {
          const int kvt = t >> 5, tt = t & 31;
          const int idx = (d >> 5) * 2 + (tt >> 4), h2 = (tt >> 3) & 1, j = tt & 7;
          Vf[bhOff + (size_t)(((kvt * 4 + idx) * 64 + h2 * 32 + (d & 31)) * 8 + j)] = (bf16_t)v;
        }
      }
    }
  }
}

// ---------------- helpers ----------------
__device__ inline int pack_bf16(float lo, float hi) {
  bf16x2 v; v[0] = (bf16_t)lo; v[1] = (bf16_t)hi;
  return __builtin_bit_cast(int, v);
}
// P-redistribution swap: ROUND-2-PROVEN inline asm. Only ever called with
// provably-distinct SSA values (different p[] packs), so no coalescing hazard.
__device__ inline void permswap(int& a, int& b) {
  asm volatile("v_permlane32_swap_b32 %0, %1" : "+v"(a), "+v"(b));
}

// Fragment-tiled loads: 4 consecutive lane-linear 16B loads (1 KB/instr).
__device__ inline void loadK4(bf16x8 k[4], const bf16_t* __restrict__ Kbase,
                              int kv0, int lane) {
  const bf16_t* p = Kbase + (size_t)(kv0 >> 5) * 2048 + lane * 8;
#pragma unroll
  for (int c = 0; c < 4; ++c) k[c] = *(const bf16x8*)(p + c * 512);
}
__device__ inline void loadV4(bf16x8 v[4], const bf16_t* __restrict__ Vbase,
                              int kv0, int lane) {
  const bf16_t* p = Vbase + (size_t)(kv0 >> 5) * 2048 + lane * 8;
#pragma unroll
  for (int idx = 0; idx < 4; ++idx) v[idx] = *(const bf16x8*)(p + idx * 512);
}

// ---------------- causal flash attention, swapped 32x32 MFMA, no LDS ----------------
// Q [BH,T,64] prescaled by (1/8)*log2e; Kf/Vf fragment-tiled; out fp32 [BH,T,64]
// Each wave: two complementary chunks c and 63-c = 65 tiles (uniform).
// XCD-locality: all 8 blocks of one bh share f&7 -> same XCD L2.
__global__ __launch_bounds__(256) void attn_fwd(const bf16_t* __restrict__ Q,
                                                const bf16_t* __restrict__ Kf,
                                                const bf16_t* __restrict__ Vf,
                                                float* __restrict__ out) {
  const int tid  = threadIdx.x;
  const int wave = tid >> 6;
  const int lane = tid & 63;
  const int l31  = lane & 31;
  const int hi   = lane >> 5;

  const int f    = blockIdx.x;          // 0..511
  const int bh   = ((f & 7) << 3) | ((f >> 3) & 7);
  const int bx   = f >> 6;              // 0..7
  const int c_lo = bx * 4 + wave;       // 0..31

  const bf16_t* Qp = Q  + (size_t)bh * T_SEQ * HD;
  const bf16_t* Kp = Kf + (size_t)bh * T_SEQ * HD;
  const bf16_t* Vp = Vf + (size_t)bh * T_SEQ * HD;
  float* op = out + (size_t)bh * T_SEQ * HD;

  for (int half = 0; half < 2; ++half) {
    const int chunk = half ? (63 - c_lo) : c_lo;
    const int q0 = chunk * 32;

    // Q fragments (B-operand: col=lane&31, k=(lane>>5)*8+i)
    bf16x8 qf[4];
#pragma unroll
    for (int c = 0; c < 4; ++c)
      qf[c] = *(const bf16x8*)&Qp[(size_t)(q0 + l31) * HD + c * 16 + hi * 8];

    f32x16 o0 = {}, o1 = {};
    float m_run = -INFINITY;
    float l_run = 0.f;          // per-lane HALF-row partial sum

    bf16x8 kA[4], vA[4];
    loadK4(kA, Kp, 0, lane);

    for (int kv0 = 0; kv0 <= q0; kv0 += 32) {
      // V for THIS tile: issue now, consumed after softmax
      loadV4(vA, Vp, kv0, lane);

      // S^T = K_tile x Q_tile^T : D[key][q], key = koff(r)+kv0, q = l31+q0
      f32x16 st = {};
      __builtin_amdgcn_s_setprio(1);
#pragma unroll
      for (int c = 0; c < 4; ++c)
        st = __builtin_amdgcn_mfma_f32_32x32x16_bf16(kA[c], qf[c], st, 0, 0, 0);
      __builtin_amdgcn_s_setprio(0);

      // prefetch K for NEXT tile (regalloc double-buffers; hides under softmax+PV)
      const int nxt = (kv0 + 32 <= q0) ? kv0 + 32 : kv0;
      loadK4(kA, Kp, nxt, lane);

      if (kv0 == q0) {   // only the diagonal tile needs causal masking
#pragma unroll
        for (int r = 0; r < 16; ++r) {
          const int koff = (r & 3) + 8 * (r >> 2) + 4 * hi;
          st[r] = (koff > l31) ? -INFINITY : st[r];
        }
      }
      // per-lane local max over this lane's 16 scores (VALU tree, no cross-lane)
      float pm = fmaxf(fmaxf(fmaxf(st[0], st[1]), fmaxf(st[2], st[3])),
                       fmaxf(fmaxf(st[4], st[5]), fmaxf(st[6], st[7])));
      pm = fmaxf(pm, fmaxf(fmaxf(fmaxf(st[8], st[9]), fmaxf(st[10], st[11])),
                           fmaxf(fmaxf(st[12], st[13]), fmaxf(st[14], st[15]))));

      // defer-max (T13): rescale only when the local max grows past m_run+8.
      // Cross-half max exchange lives ONLY here (first tile always triggers,
      // establishing row-consistent m_run across the two half-lanes).
      if (__any(!(pm <= m_run + 8.f))) {
        const float pm_full = fmaxf(pm, __shfl_xor(pm, 32));
        const float m_new = fmaxf(m_run, pm_full);
        const float alpha = exp2f(m_run - m_new);   // first tile: exp2(-inf)=0
        m_run = m_new;
        l_run *= alpha;
#pragma unroll
        for (int r = 0; r < 16; ++r) {
          const int qr = (r & 3) + 8 * (r >> 2) + 4 * hi;
          const float av = __shfl(alpha, qr);
          o0[r] *= av; o1[r] *= av;
        }
      }

      float p[16];
#pragma unroll
      for (int r = 0; r < 16; ++r) p[r] = exp2f(st[r] - m_run);
      float s0 = (p[0] + p[1]) + (p[2] + p[3]);
      float s1 = (p[4] + p[5]) + (p[6] + p[7]);
      float s2 = (p[8] + p[9]) + (p[10] + p[11]);
      float s3 = (p[12] + p[13]) + (p[14] + p[15]);
      l_run += (s0 + s1) + (s2 + s3);   // per-lane partial; halves combined at end

      // pack P to bf16 pairs; permlane32_swap redistributes into PV A-fragments
      int a01 = pack_bf16(p[0],  p[1]),  a23 = pack_bf16(p[2],  p[3]);
      int b01 = pack_bf16(p[4],  p[5]),  b23 = pack_bf16(p[6],  p[7]);
      int c01 = pack_bf16(p[8],  p[9]),  c23 = pack_bf16(p[10], p[11]);
      int d01 = pack_bf16(p[12], p[13]), d23 = pack_bf16(p[14], p[15]);
      permswap(a01, b01); permswap(a23, b23);
      permswap(c01, d01); permswap(c23, d23);
      i32x4 w1 = {a01, a23, b01, b23};   // keys kv0+0..15
      i32x4 w2 = {c01, c23, d01, d23};   // keys kv0+16..31
      bf16x8 f1 = __builtin_bit_cast(bf16x8, w1);
      bf16x8 f2 = __builtin_bit_cast(bf16x8, w2);

      // O += P @ V  (Vf rows contiguous in key)
      __builtin_amdgcn_s_setprio(1);
      o0 = __builtin_amdgcn_mfma_f32_32x32x16_bf16(f1, vA[0], o0, 0, 0, 0);
      o0 = __builtin_amdgcn_mfma_f32_32x32x16_bf16(f2, vA[1], o0, 0, 0, 0);
      o1 = __builtin_amdgcn_mfma_f32_32x32x16_bf16(f1, vA[2], o1, 0, 0, 0);
      o1 = __builtin_amdgcn_mfma_f32_32x32x16_bf16(f2, vA[3], o1, 0, 0, 0);
      __builtin_amdgcn_s_setprio(0);
    }

    // epilogue: combine l halves, out = O / l
    const float l_tot = l_run + __shfl_xor(l_run, 32);
    const float linv = 1.f / l_tot;
#pragma unroll
    for (int r = 0; r < 16; ++r) {
      const int qr = (r & 3) + 8 * (r >> 2) + 4 * hi;
      const float li = __shfl(linv, qr);
      op[(size_t)(q0 + qr) * HD + l31]      = o0[r] * li;
      op[(size_t)(q0 + qr) * HD + 32 + l31] = o1[r] * li;
    }
  }
}

extern "C" void kernel_launch(void* const* d_in, const int* in_sizes, int n_in,
                              void* d_out, int out_size, void* d_ws, size_t ws_size,
                              hipStream_t stream) {
  const float* x = (const float*)d_in[0];
  const float* W = (const float*)d_in[1];
  float* out = (float*)d_out;

  char* ws = (char*)d_ws;
  bf16_t* xb  = (bf16_t*)(ws);
  bf16_t* wb  = (bf16_t*)(ws + 16777216);
  bf16_t* Qb  = (bf16_t*)(ws + 16777216 + 6291456);
  bf16_t* Kfb = Qb + 8388608;
  bf16_t* Vfb = Kfb + 8388608;

  cvt_f32_bf16<<<2048, 256, 0, stream>>>(x, xb, (M_TOT * D_MODEL) / 4);
  cvt_f32_bf16<<<1024, 256, 0, stream>>>(W, wb, (N_TOT * D_MODEL) / 4);

  dim3 ggrid(N_TOT / 128, M_TOT / 128);   // (24, 64)
  qkv_gemm<<<ggrid, 256, 0, stream>>>(xb, wb, Qb, Kfb, Vfb);

  // 512 blocks, 1-D: f&7 selects XCD (heuristic); all 8 blocks of a bh co-locate
  attn_fwd<<<512, 256, 0, stream>>>(Qb, Kfb, Vfb, out);
}

// Round 11
// 159.827 us; speedup vs baseline: 3.5509x; 1.0362x over previous
//
#include <hip/hip_runtime.h>
#include <hip/hip_bf16.h>
#include <math.h>

#define D_MODEL 1024
#define N_HEAD  16
#define HD      64
#define B_SZ    4
#define T_SEQ   2048
#define M_TOT   (B_SZ * T_SEQ)   // 8192
#define N_TOT   (3 * D_MODEL)    // 3072

typedef __bf16 bf16_t;
typedef __bf16 bf16x8 __attribute__((ext_vector_type(8)));
typedef __bf16 bf16x4 __attribute__((ext_vector_type(4)));
typedef __bf16 bf16x2 __attribute__((ext_vector_type(2)));
typedef float  f32x4  __attribute__((ext_vector_type(4)));
typedef float  f32x16 __attribute__((ext_vector_type(16)));
typedef int    i32x4  __attribute__((ext_vector_type(4)));

// softmax scale folded with log2(e): scores end up in log2 domain -> exp2f
#define Q_PRESCALE 0.18033688011112042f   // (1/8) * log2(e)

// ---------------- fp32 -> bf16 conversion (vectorized) ----------------
__global__ __launch_bounds__(256) void cvt_f32_bf16(const float* __restrict__ in,
                                                    bf16_t* __restrict__ out, int n4) {
  int i = blockIdx.x * blockDim.x + threadIdx.x;
  int stride = gridDim.x * blockDim.x;
  for (; i < n4; i += stride) {
    float4 v = ((const float4*)in)[i];
    bf16x4 o;
    o[0] = (bf16_t)v.x; o[1] = (bf16_t)v.y; o[2] = (bf16_t)v.z; o[3] = (bf16_t)v.w;
    ((bf16x4*)out)[i] = o;
  }
}

// ---------------- QKV projection GEMM (bf16 MFMA, 128x128 tile) ----------------
// Round-11: T3/T4 pipeline — 3 staging buffers, counted s_waitcnt vmcnt(4) +
// RAW s_barrier (never __syncthreads in the K-loop: its vmcnt(0) drain was the
// ~65%-idle wall at r10). Each stage gets ~2 compute phases to land.
// Retained: LDS XOR-swizzle via pre-swizzled global source (r10: conflicts
// 6.3M -> 0), fragment-tiled Kf/Vf epilogue (r9 attn win).
//  Kf[bh][t>>5][d>>4][(d>>3)&1][t&31][d&7]
//  Vf[bh][t>>5][(d>>5)*2+((t&31)>>4)][((t&31)>>3)&1][d&31][t&7]
__global__ __launch_bounds__(256) void qkv_gemm(const bf16_t* __restrict__ xb,
                                                const bf16_t* __restrict__ wb,
                                                bf16_t* __restrict__ Q,
                                                bf16_t* __restrict__ Kf,
                                                bf16_t* __restrict__ Vf) {
  __shared__ alignas(16) bf16_t a_lds[3][128 * 32];
  __shared__ alignas(16) bf16_t b_lds[3][128 * 32];
  const int tid  = threadIdx.x;
  const int wave = tid >> 6;
  const int lane = tid & 63;
  const int bm = blockIdx.y * 128;
  const int bn = blockIdx.x * 128;

  f32x4 acc[4][4] = {};

  const int sRow  = lane >> 2;                        // row within 16-row chunk
  const int sCol8 = (lane & 3) ^ ((lane >> 3) & 3);   // pre-swizzled global col8
  const int fr = lane & 15;
  const int fk = lane >> 4;                           // fragment k-group 0..3
  const int wm = (wave >> 1) * 64;
  const int wn = (wave & 1) * 64;

  auto stage = [&](int buf, int kk) {
#pragma unroll
    for (int c = 0; c < 2; ++c) {
      const int chunk = wave * 2 + c;
      const bf16_t* gA = &xb[(size_t)(bm + chunk * 16 + sRow) * D_MODEL + kk + sCol8 * 8];
      __builtin_amdgcn_global_load_lds(
          (__attribute__((address_space(1))) void*)(void*)gA,
          (__attribute__((address_space(3))) void*)&a_lds[buf][chunk * 512], 16, 0, 0);
      const bf16_t* gB = &wb[(size_t)(bn + chunk * 16 + sRow) * D_MODEL + kk + sCol8 * 8];
      __builtin_amdgcn_global_load_lds(
          (__attribute__((address_space(1))) void*)(void*)gB,
          (__attribute__((address_space(3))) void*)&b_lds[buf][chunk * 512], 16, 0, 0);
    }
  };

  auto loadFrags = [&](int buf, bf16x8 af[4], bf16x8 bfr[4]) {
#pragma unroll
    for (int mt = 0; mt < 4; ++mt) {
      const int row = wm + mt * 16 + fr;
      af[mt] = *(const bf16x8*)&a_lds[buf][row * 32 + (fk ^ ((fr >> 1) & 3)) * 8];
    }
#pragma unroll
    for (int nt = 0; nt < 4; ++nt) {
      const int row = wn + nt * 16 + fr;
      bfr[nt] = *(const bf16x8*)&b_lds[buf][row * 32 + (fk ^ ((fr >> 1) & 3)) * 8];
    }
  };

  auto mfmaAll = [&](bf16x8 af[4], bf16x8 bfr[4]) {
    __builtin_amdgcn_s_setprio(1);
#pragma unroll
    for (int mt = 0; mt < 4; ++mt)
#pragma unroll
      for (int nt = 0; nt < 4; ++nt)
        acc[mt][nt] = __builtin_amdgcn_mfma_f32_16x16x32_bf16(af[mt], bfr[nt], acc[mt][nt], 0, 0, 0);
    __builtin_amdgcn_s_setprio(0);
  };

  // prologue: two tiles in flight
  stage(0, 0);
  stage(1, 32);
  int cur = 0;
  for (int t = 0; t < 31; ++t) {
    // stage(t) landed when <=4 newest (stage t+1) remain; NEVER drain to 0.
    asm volatile("s_waitcnt vmcnt(4)" ::: "memory");
    __builtin_amdgcn_s_barrier();            // publish stage(t); readers of buf[(t-1)%3] are done
    __builtin_amdgcn_sched_barrier(0);       // rule #18: pin MFMA/ds_read behind the wait
    bf16x8 af[4], bfr[4];
    loadFrags(cur, af, bfr);
    if (t < 30) stage((t + 2) % 3, (t + 2) * 32);
    mfmaAll(af, bfr);
    cur = (cur + 1) % 3;
  }
  asm volatile("s_waitcnt vmcnt(0)" ::: "memory");
  __builtin_amdgcn_s_barrier();
  __builtin_amdgcn_sched_barrier(0);
  {
    bf16x8 af[4], bfr[4];
    loadFrags(cur, af, bfr);
    mfmaAll(af, bfr);
  }

  // epilogue: scatter into Q (scaled), fragment-tiled Kf, Vf
  const int cRowBase = (lane >> 4) * 4;
  const int cCol     = lane & 15;
#pragma unroll
  for (int mt = 0; mt < 4; ++mt) {
#pragma unroll
    for (int nt = 0; nt < 4; ++nt) {
      const int n   = bn + wn + nt * 16 + cCol;
      const int sec = n >> 10;            // 0=Q 1=K 2=V
      const int hn  = n & 1023;
      const int h   = hn >> 6;
      const int d   = hn & 63;
#pragma unroll
      for (int r = 0; r < 4; ++r) {
        const int m = bm + wm + mt * 16 + cRowBase + r;
        const int b = m >> 11;
        const int t = m & 2047;
        const float v = acc[mt][nt][r];
        const size_t bhOff = (size_t)(b * N_HEAD + h) * (T_SEQ * HD);
        if (sec == 0) {
          Q[bhOff + (size_t)t * HD + d] = (bf16_t)(v * Q_PRESCALE);
        } else if (sec == 1) {
          const int kvt = t >> 5, lk = t & 31;
          const int cc = d >> 4, h2 = (d >> 3) & 1, j = d & 7;
          Kf[bhOff + (size_t)(((kvt * 4 + cc) * 64 + h2 * 32 + lk) * 8 + j)] = (bf16_t)v;
        } else {
          const int kvt = t >> 5, tt = t & 31;
          const int idx = (d >> 5) * 2 + (tt >> 4), h2 = (tt >> 3) & 1, j = tt & 7;
          Vf[bhOff + (size_t)(((kvt * 4 + idx) * 64 + h2 * 32 + (d & 31)) * 8 + j)] = (bf16_t)v;
        }
      }
    }
  }
}

// ---------------- helpers ----------------
__device__ inline int pack_bf16(float lo, float hi) {
  bf16x2 v; v[0] = (bf16_t)lo; v[1] = (bf16_t)hi;
  return __builtin_bit_cast(int, v);
}
// P-redistribution swap: ROUND-2-PROVEN inline asm. Only ever called with
// provably-distinct SSA values (different p[] packs), so no coalescing hazard.
__device__ inline void permswap(int& a, int& b) {
  asm volatile("v_permlane32_swap_b32 %0, %1" : "+v"(a), "+v"(b));
}

// Fragment-tiled loads: 4 consecutive lane-linear 16B loads (1 KB/instr).
__device__ inline void loadK4(bf16x8 k[4], const bf16_t* __restrict__ Kbase,
                              int kv0, int lane) {
  const bf16_t* p = Kbase + (size_t)(kv0 >> 5) * 2048 + lane * 8;
#pragma unroll
  for (int c = 0; c < 4; ++c) k[c] = *(const bf16x8*)(p + c * 512);
}
__device__ inline void loadV4(bf16x8 v[4], const bf16_t* __restrict__ Vbase,
                              int kv0, int lane) {
  const bf16_t* p = Vbase + (size_t)(kv0 >> 5) * 2048 + lane * 8;
#pragma unroll
  for (int idx = 0; idx < 4; ++idx) v[idx] = *(const bf16x8*)(p + idx * 512);
}

// ---------------- causal flash attention, swapped 32x32 MFMA, no LDS ----------------
// Q [BH,T,64] prescaled by (1/8)*log2e; Kf/Vf fragment-tiled; out fp32 [BH,T,64]
// Each wave: two complementary chunks c and 63-c = 65 tiles (uniform).
// XCD-locality: all 8 blocks of one bh share f&7 -> same XCD L2.
__global__ __launch_bounds__(256) void attn_fwd(const bf16_t* __restrict__ Q,
                                                const bf16_t* __restrict__ Kf,
                                                const bf16_t* __restrict__ Vf,
                                                float* __restrict__ out) {
  const int tid  = threadIdx.x;
  const int wave = tid >> 6;
  const int lane = tid & 63;
  const int l31  = lane & 31;
  const int hi   = lane >> 5;

  const int f    = blockIdx.x;          // 0..511
  const int bh   = ((f & 7) << 3) | ((f >> 3) & 7);
  const int bx   = f >> 6;              // 0..7
  const int c_lo = bx * 4 + wave;       // 0..31

  const bf16_t* Qp = Q  + (size_t)bh * T_SEQ * HD;
  const bf16_t* Kp = Kf + (size_t)bh * T_SEQ * HD;
  const bf16_t* Vp = Vf + (size_t)bh * T_SEQ * HD;
  float* op = out + (size_t)bh * T_SEQ * HD;

  for (int half = 0; half < 2; ++half) {
    const int chunk = half ? (63 - c_lo) : c_lo;
    const int q0 = chunk * 32;

    // Q fragments (B-operand: col=lane&31, k=(lane>>5)*8+i)
    bf16x8 qf[4];
#pragma unroll
    for (int c = 0; c < 4; ++c)
      qf[c] = *(const bf16x8*)&Qp[(size_t)(q0 + l31) * HD + c * 16 + hi * 8];

    f32x16 o0 = {}, o1 = {};
    float m_run = -INFINITY;
    float l_run = 0.f;          // per-lane HALF-row partial sum

    bf16x8 kA[4], vA[4];
    loadK4(kA, Kp, 0, lane);

    for (int kv0 = 0; kv0 <= q0; kv0 += 32) {
      // V for THIS tile: issue now, consumed after softmax
      loadV4(vA, Vp, kv0, lane);

      // S^T = K_tile x Q_tile^T : D[key][q], key = koff(r)+kv0, q = l31+q0
      f32x16 st = {};
      __builtin_amdgcn_s_setprio(1);
#pragma unroll
      for (int c = 0; c < 4; ++c)
        st = __builtin_amdgcn_mfma_f32_32x32x16_bf16(kA[c], qf[c], st, 0, 0, 0);
      __builtin_amdgcn_s_setprio(0);

      // prefetch K for NEXT tile (regalloc double-buffers; hides under softmax+PV)
      const int nxt = (kv0 + 32 <= q0) ? kv0 + 32 : kv0;
      loadK4(kA, Kp, nxt, lane);

      if (kv0 == q0) {   // only the diagonal tile needs causal masking
#pragma unroll
        for (int r = 0; r < 16; ++r) {
          const int koff = (r & 3) + 8 * (r >> 2) + 4 * hi;
          st[r] = (koff > l31) ? -INFINITY : st[r];
        }
      }
      // per-lane local max over this lane's 16 scores (VALU tree, no cross-lane)
      float pm = fmaxf(fmaxf(fmaxf(st[0], st[1]), fmaxf(st[2], st[3])),
                       fmaxf(fmaxf(st[4], st[5]), fmaxf(st[6], st[7])));
      pm = fmaxf(pm, fmaxf(fmaxf(fmaxf(st[8], st[9]), fmaxf(st[10], st[11])),
                           fmaxf(fmaxf(st[12], st[13]), fmaxf(st[14], st[15]))));

      // defer-max (T13): rescale only when the local max grows past m_run+8.
      // Cross-half max exchange lives ONLY here (first tile always triggers,
      // establishing row-consistent m_run across the two half-lanes).
      if (__any(!(pm <= m_run + 8.f))) {
        const float pm_full = fmaxf(pm, __shfl_xor(pm, 32));
        const float m_new = fmaxf(m_run, pm_full);
        const float alpha = exp2f(m_run - m_new);   // first tile: exp2(-inf)=0
        m_run = m_new;
        l_run *= alpha;
#pragma unroll
        for (int r = 0; r < 16; ++r) {
          const int qr = (r & 3) + 8 * (r >> 2) + 4 * hi;
          const float av = __shfl(alpha, qr);
          o0[r] *= av; o1[r] *= av;
        }
      }

      float p[16];
#pragma unroll
      for (int r = 0; r < 16; ++r) p[r] = exp2f(st[r] - m_run);
      float s0 = (p[0] + p[1]) + (p[2] + p[3]);
      float s1 = (p[4] + p[5]) + (p[6] + p[7]);
      float s2 = (p[8] + p[9]) + (p[10] + p[11]);
      float s3 = (p[12] + p[13]) + (p[14] + p[15]);
      l_run += (s0 + s1) + (s2 + s3);   // per-lane partial; halves combined at end

      // pack P to bf16 pairs; permlane32_swap redistributes into PV A-fragments
      int a01 = pack_bf16(p[0],  p[1]),  a23 = pack_bf16(p[2],  p[3]);
      int b01 = pack_bf16(p[4],  p[5]),  b23 = pack_bf16(p[6],  p[7]);
      int c01 = pack_bf16(p[8],  p[9]),  c23 = pack_bf16(p[10], p[11]);
      int d01 = pack_bf16(p[12], p[13]), d23 = pack_bf16(p[14], p[15]);
      permswap(a01, b01); permswap(a23, b23);
      permswap(c01, d01); permswap(c23, d23);
      i32x4 w1 = {a01, a23, b01, b23};   // keys kv0+0..15
      i32x4 w2 = {c01, c23, d01, d23};   // keys kv0+16..31
      bf16x8 f1 = __builtin_bit_cast(bf16x8, w1);
      bf16x8 f2 = __builtin_bit_cast(bf16x8, w2);

      // O += P @ V  (Vf rows contiguous in key)
      __builtin_amdgcn_s_setprio(1);
      o0 = __builtin_amdgcn_mfma_f32_32x32x16_bf16(f1, vA[0], o0, 0, 0, 0);
      o0 = __builtin_amdgcn_mfma_f32_32x32x16_bf16(f2, vA[1], o0, 0, 0, 0);
      o1 = __builtin_amdgcn_mfma_f32_32x32x16_bf16(f1, vA[2], o1, 0, 0, 0);
      o1 = __builtin_amdgcn_mfma_f32_32x32x16_bf16(f2, vA[3], o1, 0, 0, 0);
      __builtin_amdgcn_s_setprio(0);
    }

    // epilogue: combine l halves, out = O / l
    const float l_tot = l_run + __shfl_xor(l_run, 32);
    const float linv = 1.f / l_tot;
#pragma unroll
    for (int r = 0; r < 16; ++r) {
      const int qr = (r & 3) + 8 * (r >> 2) + 4 * hi;
      const float li = __shfl(linv, qr);
      op[(size_t)(q0 + qr) * HD + l31]      = o0[r] * li;
      op[(size_t)(q0 + qr) * HD + 32 + l31] = o1[r] * li;
    }
  }
}

extern "C" void kernel_launch(void* const* d_in, const int* in_sizes, int n_in,
                              void* d_out, int out_size, void* d_ws, size_t ws_size,
                              hipStream_t stream) {
  const float* x = (const float*)d_in[0];
  const float* W = (const float*)d_in[1];
  float* out = (float*)d_out;

  char* ws = (char*)d_ws;
  bf16_t* xb  = (bf16_t*)(ws);
  bf16_t* wb  = (bf16_t*)(ws + 16777216);
  bf16_t* Qb  = (bf16_t*)(ws + 16777216 + 6291456);
  bf16_t* Kfb = Qb + 8388608;
  bf16_t* Vfb = Kfb + 8388608;

  cvt_f32_bf16<<<2048, 256, 0, stream>>>(x, xb, (M_TOT * D_MODEL) / 4);
  cvt_f32_bf16<<<1024, 256, 0, stream>>>(W, wb, (N_TOT * D_MODEL) / 4);

  dim3 ggrid(N_TOT / 128, M_TOT / 128);   // (24, 64)
  qkv_gemm<<<ggrid, 256, 0, stream>>>(xb, wb, Qb, Kfb, Vfb);

  // 512 blocks, 1-D: f&7 selects XCD (heuristic); all 8 blocks of a bh co-locate
  attn_fwd<<<512, 256, 0, stream>>>(Qb, Kfb, Vfb, out);
}

// Round 12
// 153.045 us; speedup vs baseline: 3.7082x; 1.0443x over previous
//
#include <hip/hip_runtime.h>
#include <hip/hip_bf16.h>
#include <math.h>

#define D_MODEL 1024
#define N_HEAD  16
#define HD      64
#define B_SZ    4
#define T_SEQ   2048
#define M_TOT   (B_SZ * T_SEQ)   // 8192
#define N_TOT   (3 * D_MODEL)    // 3072

typedef __bf16 bf16_t;
typedef __bf16 bf16x8 __attribute__((ext_vector_type(8)));
typedef __bf16 bf16x4 __attribute__((ext_vector_type(4)));
typedef __bf16 bf16x2 __attribute__((ext_vector_type(2)));
typedef float  f32x4  __attribute__((ext_vector_type(4)));
typedef float  f32x16 __attribute__((ext_vector_type(16)));
typedef int    i32x4  __attribute__((ext_vector_type(4)));

// softmax scale folded with log2(e): scores end up in log2 domain -> exp2f
#define Q_PRESCALE 0.18033688011112042f   // (1/8) * log2(e)

// ---------------- fp32 -> bf16 conversion (vectorized) ----------------
__global__ __launch_bounds__(256) void cvt_f32_bf16(const float* __restrict__ in,
                                                    bf16_t* __restrict__ out, int n4) {
  int i = blockIdx.x * blockDim.x + threadIdx.x;
  int stride = gridDim.x * blockDim.x;
  for (; i < n4; i += stride) {
    float4 v = ((const float4*)in)[i];
    bf16x4 o;
    o[0] = (bf16_t)v.x; o[1] = (bf16_t)v.y; o[2] = (bf16_t)v.z; o[3] = (bf16_t)v.w;
    ((bf16x4*)out)[i] = o;
  }
}

// ---------------- QKV projection GEMM (bf16 MFMA, 128x128 tile) ----------------
// Round-12: epilogue rewrite (main loop frozen from r11). The r9-r11 epilogue
// did 64 scattered 2B stores/thread (fragment-tiled Kf/Vf + row-major Q) —
// ~4x the store instructions and ~16x the cache-line touches of the ideal.
//  V blocks: lane's 4 acc values are CONSECUTIVE t in Vf -> one bf16x4 8B
//            store per tile (16 stores, no LDS).
//  Q/K blocks: LDS transpose (reuse staging LDS, pitch 132) -> 16 contiguous
//            8B stores per thread.
// Layouts consumed by attention (unchanged):
//  Kf[bh][t>>5][d>>4][(d>>3)&1][t&31][d&7]
//  Vf[bh][t>>5][(d>>5)*2+((t&31)>>4)][((t&31)>>3)&1][d&31][t&7]
__global__ __launch_bounds__(256) void qkv_gemm(const bf16_t* __restrict__ xb,
                                                const bf16_t* __restrict__ wb,
                                                bf16_t* __restrict__ Q,
                                                bf16_t* __restrict__ Kf,
                                                bf16_t* __restrict__ Vf) {
  __shared__ alignas(16) bf16_t smem[24576];   // 48 KB: staging; aliased as C-tile in epilogue
  bf16_t* a_lds = smem;                        // [3][4096]
  bf16_t* b_lds = smem + 12288;                // [3][4096]
  bf16_t* c_lds = smem;                        // [128][132] bf16 (33792 B) — epilogue only

  const int tid  = threadIdx.x;
  const int wave = tid >> 6;
  const int lane = tid & 63;
  const int bm = blockIdx.y * 128;
  const int bn = blockIdx.x * 128;
  const int sec = bn >> 10;                    // whole block in one section (bn 128-aligned)

  f32x4 acc[4][4] = {};

  const int sRow  = lane >> 2;                        // row within 16-row chunk
  const int sCol8 = (lane & 3) ^ ((lane >> 3) & 3);   // pre-swizzled global col8
  const int fr = lane & 15;
  const int fk = lane >> 4;                           // fragment k-group 0..3
  const int wm = (wave >> 1) * 64;
  const int wn = (wave & 1) * 64;

  auto stage = [&](int buf, int kk) {
#pragma unroll
    for (int c = 0; c < 2; ++c) {
      const int chunk = wave * 2 + c;
      const bf16_t* gA = &xb[(size_t)(bm + chunk * 16 + sRow) * D_MODEL + kk + sCol8 * 8];
      __builtin_amdgcn_global_load_lds(
          (__attribute__((address_space(1))) void*)(void*)gA,
          (__attribute__((address_space(3))) void*)&a_lds[buf * 4096 + chunk * 512], 16, 0, 0);
      const bf16_t* gB = &wb[(size_t)(bn + chunk * 16 + sRow) * D_MODEL + kk + sCol8 * 8];
      __builtin_amdgcn_global_load_lds(
          (__attribute__((address_space(1))) void*)(void*)gB,
          (__attribute__((address_space(3))) void*)&b_lds[buf * 4096 + chunk * 512], 16, 0, 0);
    }
  };

  auto loadFrags = [&](int buf, bf16x8 af[4], bf16x8 bfr[4]) {
#pragma unroll
    for (int mt = 0; mt < 4; ++mt) {
      const int row = wm + mt * 16 + fr;
      af[mt] = *(const bf16x8*)&a_lds[buf * 4096 + row * 32 + (fk ^ ((fr >> 1) & 3)) * 8];
    }
#pragma unroll
    for (int nt = 0; nt < 4; ++nt) {
      const int row = wn + nt * 16 + fr;
      bfr[nt] = *(const bf16x8*)&b_lds[buf * 4096 + row * 32 + (fk ^ ((fr >> 1) & 3)) * 8];
    }
  };

  auto mfmaAll = [&](bf16x8 af[4], bf16x8 bfr[4]) {
    __builtin_amdgcn_s_setprio(1);
#pragma unroll
    for (int mt = 0; mt < 4; ++mt)
#pragma unroll
      for (int nt = 0; nt < 4; ++nt)
        acc[mt][nt] = __builtin_amdgcn_mfma_f32_16x16x32_bf16(af[mt], bfr[nt], acc[mt][nt], 0, 0, 0);
    __builtin_amdgcn_s_setprio(0);
  };

  // prologue: two tiles in flight
  stage(0, 0);
  stage(1, 32);
  int cur = 0;
  for (int t = 0; t < 31; ++t) {
    asm volatile("s_waitcnt vmcnt(4)" ::: "memory");   // stage(t) landed; never drain to 0
    __builtin_amdgcn_s_barrier();
    __builtin_amdgcn_sched_barrier(0);                 // rule #18
    bf16x8 af[4], bfr[4];
    loadFrags(cur, af, bfr);
    if (t < 30) stage((t + 2) % 3, (t + 2) * 32);
    mfmaAll(af, bfr);
    cur = (cur + 1) % 3;
  }
  asm volatile("s_waitcnt vmcnt(0)" ::: "memory");
  __builtin_amdgcn_s_barrier();
  __builtin_amdgcn_sched_barrier(0);
  {
    bf16x8 af[4], bfr[4];
    loadFrags(cur, af, bfr);
    mfmaAll(af, bfr);
  }

  const int cRowBase = (lane >> 4) * 4;
  const int cCol     = lane & 15;

  if (sec == 2) {
    // ---- V: direct packed stores (4 consecutive t per lane = Vf inner dim) ----
#pragma unroll
    for (int mt = 0; mt < 4; ++mt) {
#pragma unroll
      for (int nt = 0; nt < 4; ++nt) {
        const int hn = (bn & 1023) + wn + nt * 16 + cCol;
        const int h  = hn >> 6;
        const int d  = hn & 63;
        const int mbase = bm + wm + mt * 16 + cRowBase;
        const int b  = mbase >> 11;
        const int t0 = mbase & 2047;
        const int kvt = t0 >> 5, tt0 = t0 & 31;
        const int idx = (d >> 5) * 2 + (tt0 >> 4);
        const int h2  = (tt0 >> 3) & 1;
        const int j0  = tt0 & 7;                       // 0 or 4
        bf16x4 pk;
        pk[0] = (bf16_t)acc[mt][nt][0]; pk[1] = (bf16_t)acc[mt][nt][1];
        pk[2] = (bf16_t)acc[mt][nt][2]; pk[3] = (bf16_t)acc[mt][nt][3];
        const size_t bhOff = (size_t)(b * N_HEAD + h) * (T_SEQ * HD);
        *(bf16x4*)&Vf[bhOff + (size_t)(((kvt * 4 + idx) * 64 + h2 * 32 + (d & 31)) * 8 + j0)] = pk;
      }
    }
  } else {
    // ---- Q/K: LDS transpose then contiguous 8B stores ----
    __syncthreads();                                   // staging reads all done
    const float qs = (sec == 0) ? Q_PRESCALE : 1.0f;
#pragma unroll
    for (int mt = 0; mt < 4; ++mt)
#pragma unroll
      for (int nt = 0; nt < 4; ++nt)
#pragma unroll
        for (int r = 0; r < 4; ++r) {
          const int mloc = wm + mt * 16 + cRowBase + r;
          const int nloc = wn + nt * 16 + cCol;
          c_lds[mloc * 132 + nloc] = (bf16_t)(acc[mt][nt][r] * qs);
        }
    __syncthreads();

    const int row = tid >> 1;          // 0..127
    const int nh  = tid & 1;           // column half
    const int m = bm + row;
    const int b = m >> 11, t = m & 2047;
    const int h = ((bn & 1023) + nh * 64) >> 6;
    const size_t bhOff = (size_t)(b * N_HEAD + h) * (T_SEQ * HD);

    if (sec == 0) {
      bf16_t* qp = Q + bhOff + (size_t)t * HD;
#pragma unroll
      for (int o = 0; o < 16; ++o) {
        bf16x4 vv = *(const bf16x4*)&c_lds[row * 132 + nh * 64 + o * 4];
        *(bf16x4*)&qp[o * 4] = vv;
      }
    } else {
      const int kvt = t >> 5, lk = t & 31;
#pragma unroll
      for (int o = 0; o < 16; ++o) {
        const int d0 = o * 4;
        const int cc = d0 >> 4, h2 = (d0 >> 3) & 1, j0 = d0 & 7;   // j0 ∈ {0,4}
        bf16x4 vv = *(const bf16x4*)&c_lds[row * 132 + nh * 64 + d0];
        *(bf16x4*)&Kf[bhOff + (size_t)(((kvt * 4 + cc) * 64 + h2 * 32 + lk) * 8 + j0)] = vv;
      }
    }
  }
}

// ---------------- helpers ----------------
__device__ inline int pack_bf16(float lo, float hi) {
  bf16x2 v; v[0] = (bf16_t)lo; v[1] = (bf16_t)hi;
  return __builtin_bit_cast(int, v);
}
// P-redistribution swap: ROUND-2-PROVEN inline asm. Only ever called with
// provably-distinct SSA values (different p[] packs), so no coalescing hazard.
__device__ inline void permswap(int& a, int& b) {
  asm volatile("v_permlane32_swap_b32 %0, %1" : "+v"(a), "+v"(b));
}

// Fragment-tiled loads: 4 consecutive lane-linear 16B loads (1 KB/instr).
__device__ inline void loadK4(bf16x8 k[4], const bf16_t* __restrict__ Kbase,
                              int kv0, int lane) {
  const bf16_t* p = Kbase + (size_t)(kv0 >> 5) * 2048 + lane * 8;
#pragma unroll
  for (int c = 0; c < 4; ++c) k[c] = *(const bf16x8*)(p + c * 512);
}
__device__ inline void loadV4(bf16x8 v[4], const bf16_t* __restrict__ Vbase,
                              int kv0, int lane) {
  const bf16_t* p = Vbase + (size_t)(kv0 >> 5) * 2048 + lane * 8;
#pragma unroll
  for (int idx = 0; idx < 4; ++idx) v[idx] = *(const bf16x8*)(p + idx * 512);
}

// ---------------- causal flash attention, swapped 32x32 MFMA, no LDS ----------------
// Q [BH,T,64] prescaled by (1/8)*log2e; Kf/Vf fragment-tiled; out fp32 [BH,T,64]
// Each wave: two complementary chunks c and 63-c = 65 tiles (uniform).
// XCD-locality: all 8 blocks of one bh share f&7 -> same XCD L2.
__global__ __launch_bounds__(256) void attn_fwd(const bf16_t* __restrict__ Q,
                                                const bf16_t* __restrict__ Kf,
                                                const bf16_t* __restrict__ Vf,
                                                float* __restrict__ out) {
  const int tid  = threadIdx.x;
  const int wave = tid >> 6;
  const int lane = tid & 63;
  const int l31  = lane & 31;
  const int hi   = lane >> 5;

  const int f    = blockIdx.x;          // 0..511
  const int bh   = ((f & 7) << 3) | ((f >> 3) & 7);
  const int bx   = f >> 6;              // 0..7
  const int c_lo = bx * 4 + wave;       // 0..31

  const bf16_t* Qp = Q  + (size_t)bh * T_SEQ * HD;
  const bf16_t* Kp = Kf + (size_t)bh * T_SEQ * HD;
  const bf16_t* Vp = Vf + (size_t)bh * T_SEQ * HD;
  float* op = out + (size_t)bh * T_SEQ * HD;

  for (int half = 0; half < 2; ++half) {
    const int chunk = half ? (63 - c_lo) : c_lo;
    const int q0 = chunk * 32;

    // Q fragments (B-operand: col=lane&31, k=(lane>>5)*8+i)
    bf16x8 qf[4];
#pragma unroll
    for (int c = 0; c < 4; ++c)
      qf[c] = *(const bf16x8*)&Qp[(size_t)(q0 + l31) * HD + c * 16 + hi * 8];

    f32x16 o0 = {}, o1 = {};
    float m_run = -INFINITY;
    float l_run = 0.f;          // per-lane HALF-row partial sum

    bf16x8 kA[4], vA[4];
    loadK4(kA, Kp, 0, lane);

    for (int kv0 = 0; kv0 <= q0; kv0 += 32) {
      // V for THIS tile: issue now, consumed after softmax
      loadV4(vA, Vp, kv0, lane);

      // S^T = K_tile x Q_tile^T : D[key][q], key = koff(r)+kv0, q = l31+q0
      f32x16 st = {};
      __builtin_amdgcn_s_setprio(1);
#pragma unroll
      for (int c = 0; c < 4; ++c)
        st = __builtin_amdgcn_mfma_f32_32x32x16_bf16(kA[c], qf[c], st, 0, 0, 0);
      __builtin_amdgcn_s_setprio(0);

      // prefetch K for NEXT tile (regalloc double-buffers; hides under softmax+PV)
      const int nxt = (kv0 + 32 <= q0) ? kv0 + 32 : kv0;
      loadK4(kA, Kp, nxt, lane);

      if (kv0 == q0) {   // only the diagonal tile needs causal masking
#pragma unroll
        for (int r = 0; r < 16; ++r) {
          const int koff = (r & 3) + 8 * (r >> 2) + 4 * hi;
          st[r] = (koff > l31) ? -INFINITY : st[r];
        }
      }
      // per-lane local max over this lane's 16 scores (VALU tree, no cross-lane)
      float pm = fmaxf(fmaxf(fmaxf(st[0], st[1]), fmaxf(st[2], st[3])),
                       fmaxf(fmaxf(st[4], st[5]), fmaxf(st[6], st[7])));
      pm = fmaxf(pm, fmaxf(fmaxf(fmaxf(st[8], st[9]), fmaxf(st[10], st[11])),
                           fmaxf(fmaxf(st[12], st[13]), fmaxf(st[14], st[15]))));

      // defer-max (T13): rescale only when the local max grows past m_run+8.
      if (__any(!(pm <= m_run + 8.f))) {
        const float pm_full = fmaxf(pm, __shfl_xor(pm, 32));
        const float m_new = fmaxf(m_run, pm_full);
        const float alpha = exp2f(m_run - m_new);   // first tile: exp2(-inf)=0
        m_run = m_new;
        l_run *= alpha;
#pragma unroll
        for (int r = 0; r < 16; ++r) {
          const int qr = (r & 3) + 8 * (r >> 2) + 4 * hi;
          const float av = __shfl(alpha, qr);
          o0[r] *= av; o1[r] *= av;
        }
      }

      float p[16];
#pragma unroll
      for (int r = 0; r < 16; ++r) p[r] = exp2f(st[r] - m_run);
      float s0 = (p[0] + p[1]) + (p[2] + p[3]);
      float s1 = (p[4] + p[5]) + (p[6] + p[7]);
      float s2 = (p[8] + p[9]) + (p[10] + p[11]);
      float s3 = (p[12] + p[13]) + (p[14] + p[15]);
      l_run += (s0 + s1) + (s2 + s3);   // per-lane partial; halves combined at end

      // pack P to bf16 pairs; permlane32_swap redistributes into PV A-fragments
      int a01 = pack_bf16(p[0],  p[1]),  a23 = pack_bf16(p[2],  p[3]);
      int b01 = pack_bf16(p[4],  p[5]),  b23 = pack_bf16(p[6],  p[7]);
      int c01 = pack_bf16(p[8],  p[9]),  c23 = pack_bf16(p[10], p[11]);
      int d01 = pack_bf16(p[12], p[13]), d23 = pack_bf16(p[14], p[15]);
      permswap(a01, b01); permswap(a23, b23);
      permswap(c01, d01); permswap(c23, d23);
      i32x4 w1 = {a01, a23, b01, b23};   // keys kv0+0..15
      i32x4 w2 = {c01, c23, d01, d23};   // keys kv0+16..31
      bf16x8 f1 = __builtin_bit_cast(bf16x8, w1);
      bf16x8 f2 = __builtin_bit_cast(bf16x8, w2);

      // O += P @ V  (Vf rows contiguous in key)
      __builtin_amdgcn_s_setprio(1);
      o0 = __builtin_amdgcn_mfma_f32_32x32x16_bf16(f1, vA[0], o0, 0, 0, 0);
      o0 = __builtin_amdgcn_mfma_f32_32x32x16_bf16(f2, vA[1], o0, 0, 0, 0);
      o1 = __builtin_amdgcn_mfma_f32_32x32x16_bf16(f1, vA[2], o1, 0, 0, 0);
      o1 = __builtin_amdgcn_mfma_f32_32x32x16_bf16(f2, vA[3], o1, 0, 0, 0);
      __builtin_amdgcn_s_setprio(0);
    }

    // epilogue: combine l halves, out = O / l
    const float l_tot = l_run + __shfl_xor(l_run, 32);
    const float linv = 1.f / l_tot;
#pragma unroll
    for (int r = 0; r < 16; ++r) {
      const int qr = (r & 3) + 8 * (r >> 2) + 4 * hi;
      const float li = __shfl(linv, qr);
      op[(size_t)(q0 + qr) * HD + l31]      = o0[r] * li;
      op[(size_t)(q0 + qr) * HD + 32 + l31] = o1[r] * li;
    }
  }
}

extern "C" void kernel_launch(void* const* d_in, const int* in_sizes, int n_in,
                              void* d_out, int out_size, void* d_ws, size_t ws_size,
                              hipStream_t stream) {
  const float* x = (const float*)d_in[0];
  const float* W = (const float*)d_in[1];
  float* out = (float*)d_out;

  char* ws = (char*)d_ws;
  bf16_t* xb  = (bf16_t*)(ws);
  bf16_t* wb  = (bf16_t*)(ws + 16777216);
  bf16_t* Qb  = (bf16_t*)(ws + 16777216 + 6291456);
  bf16_t* Kfb = Qb + 8388608;
  bf16_t* Vfb = Kfb + 8388608;

  cvt_f32_bf16<<<2048, 256, 0, stream>>>(x, xb, (M_TOT * D_MODEL) / 4);
  cvt_f32_bf16<<<1024, 256, 0, stream>>>(W, wb, (N_TOT * D_MODEL) / 4);

  dim3 ggrid(N_TOT / 128, M_TOT / 128);   // (24, 64)
  qkv_gemm<<<ggrid, 256, 0, stream>>>(xb, wb, Qb, Kfb, Vfb);

  // 512 blocks, 1-D: f&7 selects XCD (heuristic); all 8 blocks of a bh co-locate
  attn_fwd<<<512, 256, 0, stream>>>(Qb, Kfb, Vfb, out);
}

// Round 13
// 151.295 us; speedup vs baseline: 3.7511x; 1.0116x over previous
//
#include <hip/hip_runtime.h>
#include <hip/hip_bf16.h>
#include <math.h>

#define D_MODEL 1024
#define N_HEAD  16
#define HD      64
#define B_SZ    4
#define T_SEQ   2048
#define M_TOT   (B_SZ * T_SEQ)   // 8192
#define N_TOT   (3 * D_MODEL)    // 3072

typedef __bf16 bf16_t;
typedef __bf16 bf16x8 __attribute__((ext_vector_type(8)));
typedef __bf16 bf16x4 __attribute__((ext_vector_type(4)));
typedef __bf16 bf16x2 __attribute__((ext_vector_type(2)));
typedef float  f32x4  __attribute__((ext_vector_type(4)));
typedef float  f32x16 __attribute__((ext_vector_type(16)));
typedef int    i32x4  __attribute__((ext_vector_type(4)));

// softmax scale folded with log2(e): scores end up in log2 domain -> exp2f
#define Q_PRESCALE 0.18033688011112042f   // (1/8) * log2(e)

// ---------------- fp32 -> bf16 conversion (vectorized) ----------------
__global__ __launch_bounds__(256) void cvt_f32_bf16(const float* __restrict__ in,
                                                    bf16_t* __restrict__ out, int n4) {
  int i = blockIdx.x * blockDim.x + threadIdx.x;
  int stride = gridDim.x * blockDim.x;
  for (; i < n4; i += stride) {
    float4 v = ((const float4*)in)[i];
    bf16x4 o;
    o[0] = (bf16_t)v.x; o[1] = (bf16_t)v.y; o[2] = (bf16_t)v.z; o[3] = (bf16_t)v.w;
    ((bf16x4*)out)[i] = o;
  }
}

// ---------------- QKV projection GEMM (bf16 MFMA, 128x128 tile) ----------------
// (frozen from r12: 3-buf counted-vmcnt pipeline + pre-swizzled staging +
//  packed/LDS-transpose epilogue)
//  Kf[bh][t>>5][d>>4][(d>>3)&1][t&31][d&7]
//  Vf[bh][t>>5][(d>>5)*2+((t&31)>>4)][((t&31)>>3)&1][d&31][t&7]
__global__ __launch_bounds__(256) void qkv_gemm(const bf16_t* __restrict__ xb,
                                                const bf16_t* __restrict__ wb,
                                                bf16_t* __restrict__ Q,
                                                bf16_t* __restrict__ Kf,
                                                bf16_t* __restrict__ Vf) {
  __shared__ alignas(16) bf16_t smem[24576];   // 48 KB: staging; aliased as C-tile in epilogue
  bf16_t* a_lds = smem;                        // [3][4096]
  bf16_t* b_lds = smem + 12288;                // [3][4096]
  bf16_t* c_lds = smem;                        // [128][132] bf16 — epilogue only

  const int tid  = threadIdx.x;
  const int wave = tid >> 6;
  const int lane = tid & 63;
  const int bm = blockIdx.y * 128;
  const int bn = blockIdx.x * 128;
  const int sec = bn >> 10;                    // whole block in one section

  f32x4 acc[4][4] = {};

  const int sRow  = lane >> 2;
  const int sCol8 = (lane & 3) ^ ((lane >> 3) & 3);   // pre-swizzled global col8
  const int fr = lane & 15;
  const int fk = lane >> 4;
  const int wm = (wave >> 1) * 64;
  const int wn = (wave & 1) * 64;

  auto stage = [&](int buf, int kk) {
#pragma unroll
    for (int c = 0; c < 2; ++c) {
      const int chunk = wave * 2 + c;
      const bf16_t* gA = &xb[(size_t)(bm + chunk * 16 + sRow) * D_MODEL + kk + sCol8 * 8];
      __builtin_amdgcn_global_load_lds(
          (__attribute__((address_space(1))) void*)(void*)gA,
          (__attribute__((address_space(3))) void*)&a_lds[buf * 4096 + chunk * 512], 16, 0, 0);
      const bf16_t* gB = &wb[(size_t)(bn + chunk * 16 + sRow) * D_MODEL + kk + sCol8 * 8];
      __builtin_amdgcn_global_load_lds(
          (__attribute__((address_space(1))) void*)(void*)gB,
          (__attribute__((address_space(3))) void*)&b_lds[buf * 4096 + chunk * 512], 16, 0, 0);
    }
  };

  auto loadFrags = [&](int buf, bf16x8 af[4], bf16x8 bfr[4]) {
#pragma unroll
    for (int mt = 0; mt < 4; ++mt) {
      const int row = wm + mt * 16 + fr;
      af[mt] = *(const bf16x8*)&a_lds[buf * 4096 + row * 32 + (fk ^ ((fr >> 1) & 3)) * 8];
    }
#pragma unroll
    for (int nt = 0; nt < 4; ++nt) {
      const int row = wn + nt * 16 + fr;
      bfr[nt] = *(const bf16x8*)&b_lds[buf * 4096 + row * 32 + (fk ^ ((fr >> 1) & 3)) * 8];
    }
  };

  auto mfmaAll = [&](bf16x8 af[4], bf16x8 bfr[4]) {
    __builtin_amdgcn_s_setprio(1);
#pragma unroll
    for (int mt = 0; mt < 4; ++mt)
#pragma unroll
      for (int nt = 0; nt < 4; ++nt)
        acc[mt][nt] = __builtin_amdgcn_mfma_f32_16x16x32_bf16(af[mt], bfr[nt], acc[mt][nt], 0, 0, 0);
    __builtin_amdgcn_s_setprio(0);
  };

  stage(0, 0);
  stage(1, 32);
  int cur = 0;
  for (int t = 0; t < 31; ++t) {
    asm volatile("s_waitcnt vmcnt(4)" ::: "memory");
    __builtin_amdgcn_s_barrier();
    __builtin_amdgcn_sched_barrier(0);
    bf16x8 af[4], bfr[4];
    loadFrags(cur, af, bfr);
    if (t < 30) stage((t + 2) % 3, (t + 2) * 32);
    mfmaAll(af, bfr);
    cur = (cur + 1) % 3;
  }
  asm volatile("s_waitcnt vmcnt(0)" ::: "memory");
  __builtin_amdgcn_s_barrier();
  __builtin_amdgcn_sched_barrier(0);
  {
    bf16x8 af[4], bfr[4];
    loadFrags(cur, af, bfr);
    mfmaAll(af, bfr);
  }

  const int cRowBase = (lane >> 4) * 4;
  const int cCol     = lane & 15;

  if (sec == 2) {
    // ---- V: direct packed 8B stores ----
#pragma unroll
    for (int mt = 0; mt < 4; ++mt) {
#pragma unroll
      for (int nt = 0; nt < 4; ++nt) {
        const int hn = (bn & 1023) + wn + nt * 16 + cCol;
        const int h  = hn >> 6;
        const int d  = hn & 63;
        const int mbase = bm + wm + mt * 16 + cRowBase;
        const int b  = mbase >> 11;
        const int t0 = mbase & 2047;
        const int kvt = t0 >> 5, tt0 = t0 & 31;
        const int idx = (d >> 5) * 2 + (tt0 >> 4);
        const int h2  = (tt0 >> 3) & 1;
        const int j0  = tt0 & 7;
        bf16x4 pk;
        pk[0] = (bf16_t)acc[mt][nt][0]; pk[1] = (bf16_t)acc[mt][nt][1];
        pk[2] = (bf16_t)acc[mt][nt][2]; pk[3] = (bf16_t)acc[mt][nt][3];
        const size_t bhOff = (size_t)(b * N_HEAD + h) * (T_SEQ * HD);
        *(bf16x4*)&Vf[bhOff + (size_t)(((kvt * 4 + idx) * 64 + h2 * 32 + (d & 31)) * 8 + j0)] = pk;
      }
    }
  } else {
    // ---- Q/K: LDS transpose then contiguous 8B stores ----
    __syncthreads();
    const float qs = (sec == 0) ? Q_PRESCALE : 1.0f;
#pragma unroll
    for (int mt = 0; mt < 4; ++mt)
#pragma unroll
      for (int nt = 0; nt < 4; ++nt)
#pragma unroll
        for (int r = 0; r < 4; ++r) {
          const int mloc = wm + mt * 16 + cRowBase + r;
          const int nloc = wn + nt * 16 + cCol;
          c_lds[mloc * 132 + nloc] = (bf16_t)(acc[mt][nt][r] * qs);
        }
    __syncthreads();

    const int row = tid >> 1;
    const int nh  = tid & 1;
    const int m = bm + row;
    const int b = m >> 11, t = m & 2047;
    const int h = ((bn & 1023) + nh * 64) >> 6;
    const size_t bhOff = (size_t)(b * N_HEAD + h) * (T_SEQ * HD);

    if (sec == 0) {
      bf16_t* qp = Q + bhOff + (size_t)t * HD;
#pragma unroll
      for (int o = 0; o < 16; ++o) {
        bf16x4 vv = *(const bf16x4*)&c_lds[row * 132 + nh * 64 + o * 4];
        *(bf16x4*)&qp[o * 4] = vv;
      }
    } else {
      const int kvt = t >> 5, lk = t & 31;
#pragma unroll
      for (int o = 0; o < 16; ++o) {
        const int d0 = o * 4;
        const int cc = d0 >> 4, h2 = (d0 >> 3) & 1, j0 = d0 & 7;
        bf16x4 vv = *(const bf16x4*)&c_lds[row * 132 + nh * 64 + d0];
        *(bf16x4*)&Kf[bhOff + (size_t)(((kvt * 4 + cc) * 64 + h2 * 32 + lk) * 8 + j0)] = vv;
      }
    }
  }
}

// ---------------- helpers ----------------
__device__ inline int pack_bf16(float lo, float hi) {
  bf16x2 v; v[0] = (bf16_t)lo; v[1] = (bf16_t)hi;
  return __builtin_bit_cast(int, v);
}
__device__ inline void permswap(int& a, int& b) {
  asm volatile("v_permlane32_swap_b32 %0, %1" : "+v"(a), "+v"(b));
}
__device__ inline void loadK4(bf16x8 k[4], const bf16_t* __restrict__ Kbase,
                              int kv0, int lane) {
  const bf16_t* p = Kbase + (size_t)(kv0 >> 5) * 2048 + lane * 8;
#pragma unroll
  for (int c = 0; c < 4; ++c) k[c] = *(const bf16x8*)(p + c * 512);
}
__device__ inline void loadV4(bf16x8 v[4], const bf16_t* __restrict__ Vbase,
                              int kv0, int lane) {
  const bf16_t* p = Vbase + (size_t)(kv0 >> 5) * 2048 + lane * 8;
#pragma unroll
  for (int idx = 0; idx < 4; ++idx) v[idx] = *(const bf16x8*)(p + idx * 512);
}

// ---------------- causal flash attention, KV-split + in-block merge ----------------
// Round-13: 2048 blocks (bh x pair), 4 waves. Waves 0/1 split chunk pr's KV
// range in half; waves 2/3 split chunk 63-pr. Writers (odd waves) deposit
// (m,l,o) in LDS; mergers (even waves) flash-merge after one barrier.
// Doubles resident waves/SIMD (2 -> 4) to hide the per-tile serial chain
// (r12: occupancy 18.6%, VALU 66%). Tile math unchanged from r12.
__global__ __launch_bounds__(256, 4) void attn_fwd(const bf16_t* __restrict__ Q,
                                                   const bf16_t* __restrict__ Kf,
                                                   const bf16_t* __restrict__ Vf,
                                                   float* __restrict__ out) {
  __shared__ float o_sh[2][64][33];    // [grp][lane][r] pad 33 -> conflict-free
  __shared__ float m_sh[2][32];
  __shared__ float l_sh[2][32];

  const int tid  = threadIdx.x;
  const int wave = tid >> 6;
  const int lane = tid & 63;
  const int l31  = lane & 31;
  const int hi   = lane >> 5;

  const int f   = blockIdx.x;                  // 0..2047
  const int bh  = ((f & 7) << 3) | ((f >> 3) & 7);
  const int pr  = f >> 6;                      // 0..31
  const int grp = wave >> 1;                   // 0: chunk pr, 1: chunk 63-pr
  const int isWriter = wave & 1;
  const int chunk = grp ? (63 - pr) : pr;
  const int q0 = chunk * 32;
  const int n  = chunk + 1;                    // tiles in this chunk
  const int h  = (n + 1) >> 1;                 // merger gets [0,h), writer [h,n)
  const int j0 = isWriter ? h : 0;
  const int j1 = isWriter ? n : h;

  const bf16_t* Qp = Q  + (size_t)bh * T_SEQ * HD;
  const bf16_t* Kp = Kf + (size_t)bh * T_SEQ * HD;
  const bf16_t* Vp = Vf + (size_t)bh * T_SEQ * HD;
  float* op = out + (size_t)bh * T_SEQ * HD;

  // Q fragments (B-operand: col=lane&31, k=(lane>>5)*8+i)
  bf16x8 qf[4];
#pragma unroll
  for (int c = 0; c < 4; ++c)
    qf[c] = *(const bf16x8*)&Qp[(size_t)(q0 + l31) * HD + c * 16 + hi * 8];

  f32x16 o0 = {}, o1 = {};
  float m_run = -INFINITY;
  float l_run = 0.f;          // per-lane HALF-row partial sum

  if (j0 < j1) {
    bf16x8 kA[4], vA[4];
    loadK4(kA, Kp, j0 * 32, lane);

    for (int j = j0; j < j1; ++j) {
      const int kv0 = j * 32;
      loadV4(vA, Vp, kv0, lane);

      f32x16 st = {};
      __builtin_amdgcn_s_setprio(1);
#pragma unroll
      for (int c = 0; c < 4; ++c)
        st = __builtin_amdgcn_mfma_f32_32x32x16_bf16(kA[c], qf[c], st, 0, 0, 0);
      __builtin_amdgcn_s_setprio(0);

      const int nxt = (j + 1 < j1) ? (j + 1) * 32 : kv0;
      loadK4(kA, Kp, nxt, lane);

      if (kv0 == q0) {   // diagonal tile
#pragma unroll
        for (int r = 0; r < 16; ++r) {
          const int koff = (r & 3) + 8 * (r >> 2) + 4 * hi;
          st[r] = (koff > l31) ? -INFINITY : st[r];
        }
      }
      float pm = fmaxf(fmaxf(fmaxf(st[0], st[1]), fmaxf(st[2], st[3])),
                       fmaxf(fmaxf(st[4], st[5]), fmaxf(st[6], st[7])));
      pm = fmaxf(pm, fmaxf(fmaxf(fmaxf(st[8], st[9]), fmaxf(st[10], st[11])),
                           fmaxf(fmaxf(st[12], st[13]), fmaxf(st[14], st[15]))));

      if (__any(!(pm <= m_run + 8.f))) {
        const float pm_full = fmaxf(pm, __shfl_xor(pm, 32));
        const float m_new = fmaxf(m_run, pm_full);
        const float alpha = exp2f(m_run - m_new);
        m_run = m_new;
        l_run *= alpha;
#pragma unroll
        for (int r = 0; r < 16; ++r) {
          const int qr = (r & 3) + 8 * (r >> 2) + 4 * hi;
          const float av = __shfl(alpha, qr);
          o0[r] *= av; o1[r] *= av;
        }
      }

      float p[16];
#pragma unroll
      for (int r = 0; r < 16; ++r) p[r] = exp2f(st[r] - m_run);
      float s0 = (p[0] + p[1]) + (p[2] + p[3]);
      float s1 = (p[4] + p[5]) + (p[6] + p[7]);
      float s2 = (p[8] + p[9]) + (p[10] + p[11]);
      float s3 = (p[12] + p[13]) + (p[14] + p[15]);
      l_run += (s0 + s1) + (s2 + s3);

      int a01 = pack_bf16(p[0],  p[1]),  a23 = pack_bf16(p[2],  p[3]);
      int b01 = pack_bf16(p[4],  p[5]),  b23 = pack_bf16(p[6],  p[7]);
      int c01 = pack_bf16(p[8],  p[9]),  c23 = pack_bf16(p[10], p[11]);
      int d01 = pack_bf16(p[12], p[13]), d23 = pack_bf16(p[14], p[15]);
      permswap(a01, b01); permswap(a23, b23);
      permswap(c01, d01); permswap(c23, d23);
      i32x4 w1 = {a01, a23, b01, b23};
      i32x4 w2 = {c01, c23, d01, d23};
      bf16x8 f1 = __builtin_bit_cast(bf16x8, w1);
      bf16x8 f2 = __builtin_bit_cast(bf16x8, w2);

      __builtin_amdgcn_s_setprio(1);
      o0 = __builtin_amdgcn_mfma_f32_32x32x16_bf16(f1, vA[0], o0, 0, 0, 0);
      o0 = __builtin_amdgcn_mfma_f32_32x32x16_bf16(f2, vA[1], o0, 0, 0, 0);
      o1 = __builtin_amdgcn_mfma_f32_32x32x16_bf16(f1, vA[2], o1, 0, 0, 0);
      o1 = __builtin_amdgcn_mfma_f32_32x32x16_bf16(f2, vA[3], o1, 0, 0, 0);
      __builtin_amdgcn_s_setprio(0);
    }
  }

  const float l_comb = l_run + __shfl_xor(l_run, 32);   // full-row partial sum

  if (isWriter) {
#pragma unroll
    for (int r = 0; r < 16; ++r) {
      o_sh[grp][lane][r]      = o0[r];
      o_sh[grp][lane][16 + r] = o1[r];
    }
    if (lane < 32) {
      m_sh[grp][lane] = m_run;
      l_sh[grp][lane] = l_comb;
    }
  }
  __syncthreads();
  if (!isWriter) {
    // flash-merge: m=max, o = oA*aA + oB*aB, l likewise; then divide & store.
#pragma unroll
    for (int r = 0; r < 16; ++r) {
      const int qr = (r & 3) + 8 * (r >> 2) + 4 * hi;
      const float mB = m_sh[grp][qr];
      const float lB = l_sh[grp][qr];
      const float mA = __shfl(m_run, qr);     // merger never empty -> finite
      const float lA = __shfl(l_comb, qr);
      const float mM = fmaxf(mA, mB);
      const float aA = exp2f(mA - mM);
      const float aB = exp2f(mB - mM);        // empty writer: exp2(-inf)=0
      const float li = 1.f / (lA * aA + lB * aB);
      const float x0 = (o0[r] * aA + o_sh[grp][lane][r]      * aB) * li;
      const float x1 = (o1[r] * aA + o_sh[grp][lane][16 + r] * aB) * li;
      op[(size_t)(q0 + qr) * HD + l31]      = x0;
      op[(size_t)(q0 + qr) * HD + 32 + l31] = x1;
    }
  }
}

extern "C" void kernel_launch(void* const* d_in, const int* in_sizes, int n_in,
                              void* d_out, int out_size, void* d_ws, size_t ws_size,
                              hipStream_t stream) {
  const float* x = (const float*)d_in[0];
  const float* W = (const float*)d_in[1];
  float* out = (float*)d_out;

  char* ws = (char*)d_ws;
  bf16_t* xb  = (bf16_t*)(ws);
  bf16_t* wb  = (bf16_t*)(ws + 16777216);
  bf16_t* Qb  = (bf16_t*)(ws + 16777216 + 6291456);
  bf16_t* Kfb = Qb + 8388608;
  bf16_t* Vfb = Kfb + 8388608;

  cvt_f32_bf16<<<2048, 256, 0, stream>>>(x, xb, (M_TOT * D_MODEL) / 4);
  cvt_f32_bf16<<<1024, 256, 0, stream>>>(W, wb, (N_TOT * D_MODEL) / 4);

  dim3 ggrid(N_TOT / 128, M_TOT / 128);   // (24, 64)
  qkv_gemm<<<ggrid, 256, 0, stream>>>(xb, wb, Qb, Kfb, Vfb);

  // 2048 blocks: f&7 = XCD (all blocks of a bh co-locate); f>>6 = pair index
  attn_fwd<<<2048, 256, 0, stream>>>(Qb, Kfb, Vfb, out);
}